// Round 1
// baseline (2333.011 us; speedup 1.0000x reference)
//
#include <hip/hip_runtime.h>
#include <hip/hip_bf16.h>
#include <math.h>

#define HDIM 1024
#define NB 32
#define LA 2048
#define LO 32

__device__ __forceinline__ float tanh_fast(float x){
    // tanh(x) = 2/(1+e^{-2x}) - 1 ; |x| large -> saturates correctly (+/-1)
    return 2.0f / (1.0f + __expf(-2.0f * x)) - 1.0f;
}

__global__ void zero_kernel(float* __restrict__ p, int n){
    int i = blockIdx.x * blockDim.x + threadIdx.x;
    int stride = gridDim.x * blockDim.x;
    for (; i < n; i += stride) p[i] = 0.0f;
}

__global__ void gather_kernel(const float* __restrict__ qc, const int* __restrict__ ans,
                              float* __restrict__ oqc){
    int b = blockIdx.x, tid = threadIdx.x;
    int idx = ans[b];
    const float* src = qc + ((size_t)b * 64 + idx) * HDIM;
    float* dst = oqc + (size_t)b * HDIM;
    #pragma unroll
    for (int l = 0; l < 4; l++) dst[tid + l * 256] = src[tid + l * 256];
}

// out[g,h] = bias[h] + dot(in[g,:], W[h,:])   grid (G, 4), block 256
__global__ void proj_kernel(const float* __restrict__ in, const float* __restrict__ W,
                            const float* __restrict__ bias, float* __restrict__ out){
    __shared__ float xin[HDIM];
    int g = blockIdx.x, tid = threadIdx.x;
    #pragma unroll
    for (int l = 0; l < 4; l++) xin[tid + l * 256] = in[(size_t)g * HDIM + tid + l * 256];
    __syncthreads();
    int h = blockIdx.y * 256 + tid;
    float acc = bias[h];
    const float* Wr = W + (size_t)h * HDIM;
    for (int k = 0; k < HDIM; k += 4){
        float4 wv = *(const float4*)&Wr[k];
        acc += xin[k] * wv.x + xin[k+1] * wv.y + xin[k+2] * wv.z + xin[k+3] * wv.w;
    }
    out[(size_t)g * HDIM + h] = acc;
}

// Fused: s[r] += sum_{h in chunk} tanh(Qp[b,h] + Kb[h] + dot(X[r,:], Kw[h,:])) * vw[h]
// X: M x 1024 rows; b = r / rows_per_batch. grid (M/64, 8), block 256.
#define BM 64
#define BN 128
#define BK 32
__global__ __launch_bounds__(256) void score_kernel(
    const float* __restrict__ X, const float* __restrict__ Kw,
    const float* __restrict__ Kb, const float* __restrict__ Qp,
    const float* __restrict__ vw, float* __restrict__ s, int rows_per_batch)
{
    __shared__ float As[BM][BK + 4];   // 64 x 36
    __shared__ float Wt[BK][BN];       // Wt[k][h], 32 x 128
    const int tid = threadIdx.x;
    const int tx = tid & 15, ty = tid >> 4;
    const int row0 = blockIdx.x * BM;
    const int h0 = blockIdx.y * BN;

    float acc[4][8];
    #pragma unroll
    for (int i = 0; i < 4; i++)
        #pragma unroll
        for (int j = 0; j < 8; j++) acc[i][j] = 0.f;

    for (int k0 = 0; k0 < HDIM; k0 += BK){
        #pragma unroll
        for (int l = 0; l < 2; l++){
            int f = tid + l * 256;
            int r = f >> 3, c4 = (f & 7) * 4;
            float4 v = *(const float4*)(X + (size_t)(row0 + r) * HDIM + k0 + c4);
            *(float4*)&As[r][c4] = v;
        }
        #pragma unroll
        for (int l = 0; l < 4; l++){
            int f = tid + l * 256;
            int r = f >> 3, c4 = (f & 7) * 4;
            float4 v = *(const float4*)(Kw + (size_t)(h0 + r) * HDIM + k0 + c4);
            Wt[c4 + 0][r] = v.x; Wt[c4 + 1][r] = v.y;
            Wt[c4 + 2][r] = v.z; Wt[c4 + 3][r] = v.w;
        }
        __syncthreads();
        #pragma unroll
        for (int kk = 0; kk < BK; kk++){
            float av[4];
            #pragma unroll
            for (int i = 0; i < 4; i++) av[i] = As[ty * 4 + i][kk];
            float wv[8];
            *(float4*)&wv[0] = *(const float4*)&Wt[kk][tx * 8];
            *(float4*)&wv[4] = *(const float4*)&Wt[kk][tx * 8 + 4];
            #pragma unroll
            for (int i = 0; i < 4; i++)
                #pragma unroll
                for (int j = 0; j < 8; j++)
                    acc[i][j] = fmaf(av[i], wv[j], acc[i][j]);
        }
        __syncthreads();
    }

    // epilogue: tanh + dot with vw over this h-chunk, reduce across tx, atomic per row
    #pragma unroll
    for (int i = 0; i < 4; i++){
        int r = row0 + ty * 4 + i;
        int b = r / rows_per_batch;
        float p = 0.f;
        #pragma unroll
        for (int j = 0; j < 8; j++){
            int h = h0 + tx * 8 + j;
            float x = acc[i][j] + Kb[h] + Qp[(size_t)b * HDIM + h];
            p += tanh_fast(x) * vw[h];
        }
        #pragma unroll
        for (int off = 8; off > 0; off >>= 1) p += __shfl_down(p, off, 16);
        if (tx == 0) atomicAdd(&s[r], p);
    }
}

// in-place softmax over groups of Rg, grid = G blocks of 256
__global__ void softmax_kernel(float* __restrict__ s, int Rg){
    __shared__ float red[4];
    int g = blockIdx.x, tid = threadIdx.x;
    float* sg = s + (size_t)g * Rg;
    float m = -INFINITY;
    for (int i = tid; i < Rg; i += 256) m = fmaxf(m, sg[i]);
    #pragma unroll
    for (int off = 32; off > 0; off >>= 1) m = fmaxf(m, __shfl_down(m, off, 64));
    if ((tid & 63) == 0) red[tid >> 6] = m;
    __syncthreads();
    m = fmaxf(fmaxf(red[0], red[1]), fmaxf(red[2], red[3]));
    __syncthreads();
    float sum = 0.f;
    for (int i = tid; i < Rg; i += 256){ float e = __expf(sg[i] - m); sg[i] = e; sum += e; }
    #pragma unroll
    for (int off = 32; off > 0; off >>= 1) sum += __shfl_down(sum, off, 64);
    if ((tid & 63) == 0) red[tid >> 6] = sum;
    __syncthreads();
    float inv = 1.0f / (red[0] + red[1] + red[2] + red[3]);
    for (int i = tid; i < Rg; i += 256) sg[i] *= inv;
}

// out[g,k] += sum_i sc[g,i0+i] * X[g, i0+i, k]  grid (G*4, ichunks), block 256
__global__ void wsum_kernel(const float* __restrict__ X, const float* __restrict__ sc,
                            float* __restrict__ out, int Rg, int rowsPerChunk){
    __shared__ float scs[256];
    int g = blockIdx.x >> 2;
    int kc = blockIdx.x & 3;
    int i0 = blockIdx.y * rowsPerChunk;
    int tid = threadIdx.x;
    if (tid < rowsPerChunk) scs[tid] = sc[(size_t)g * Rg + i0 + tid];
    __syncthreads();
    int k = kc * 256 + tid;
    const float* Xg = X + ((size_t)g * Rg + i0) * HDIM + k;
    float acc = 0.f;
    for (int i = 0; i < rowsPerChunk; i++)
        acc += scs[i] * Xg[(size_t)i * HDIM];
    atomicAdd(&out[(size_t)g * HDIM + k], acc);
}

// logits[b,j] = fb[j] + dot(feats[b,:5120], fw[j,:5120])  grid 32, block 256
__global__ void final_kernel(const float* __restrict__ feats, const float* __restrict__ fw,
                             const float* __restrict__ fb, float* __restrict__ out){
    __shared__ float red[4];
    int b = blockIdx.x, tid = threadIdx.x;
    const float* fe = feats + (size_t)b * 5120;
    for (int j = 0; j < 5; j++){
        float acc = 0.f;
        for (int i = tid; i < 5120; i += 256) acc += fe[i] * fw[(size_t)j * 5120 + i];
        #pragma unroll
        for (int off = 32; off > 0; off >>= 1) acc += __shfl_down(acc, off, 64);
        if ((tid & 63) == 0) red[tid >> 6] = acc;
        __syncthreads();
        if (tid == 0) out[b * 5 + j] = fb[j] + red[0] + red[1] + red[2] + red[3];
        __syncthreads();
    }
}

extern "C" void kernel_launch(void* const* d_in, const int* in_sizes, int n_in,
                              void* d_out, int out_size, void* d_ws, size_t ws_size,
                              hipStream_t stream) {
    const float* article  = (const float*)d_in[0];
    const float* question = (const float*)d_in[1];
    const float* options  = (const float*)d_in[2];
    const int*   ans      = (const int*)d_in[3];
    const float* a_Qw = (const float*)d_in[4];  const float* a_Qb = (const float*)d_in[5];
    const float* a_Kw = (const float*)d_in[6];  const float* a_Kb = (const float*)d_in[7];
    const float* a_Vw = (const float*)d_in[8];  const float* a_Vb = (const float*)d_in[9];
    const float* a_vw = (const float*)d_in[10];
    const float* d_Qw = (const float*)d_in[12]; const float* d_Qb = (const float*)d_in[13];
    const float* d_Kw = (const float*)d_in[14]; const float* d_Kb = (const float*)d_in[15];
    const float* d_Vw = (const float*)d_in[16]; const float* d_Vb = (const float*)d_in[17];
    const float* d_vw = (const float*)d_in[18];
    const float* f_w  = (const float*)d_in[20]; const float* f_b  = (const float*)d_in[21];
    float* out = (float*)d_out;

    float* ws = (float*)d_ws;
    float* oqc   = ws;              // 32768
    float* qp_a  = ws + 32768;      // 32768
    float* s_art = ws + 65536;      // 65536  (zeroed)
    float* s_opt = ws + 131072;     // 5120   (zeroed)
    float* w_art = ws + 136192;     // 32768  (zeroed)
    float* wd    = ws + 168960;     // 163840 (zeroed)
    float* aq    = ws + 332800;     // 32768
    float* qp_d  = ws + 365568;     // 32768
    float* feats = ws + 398336;     // 163840

    zero_kernel<<<256, 256, 0, stream>>>(ws + 65536, 267264);
    gather_kernel<<<NB, 256, 0, stream>>>(question, ans, oqc);
    proj_kernel<<<dim3(NB, 4), 256, 0, stream>>>(oqc, a_Qw, a_Qb, qp_a);
    // article attention scores (fused Kp GEMM + tanh + vw-dot)
    score_kernel<<<dim3((NB * LA) / BM, HDIM / BN), 256, 0, stream>>>(
        article, a_Kw, a_Kb, qp_a, a_vw, s_art, LA);
    softmax_kernel<<<NB, 256, 0, stream>>>(s_art, LA);
    wsum_kernel<<<dim3(NB * 4, 8), 256, 0, stream>>>(article, s_art, w_art, LA, 256);
    proj_kernel<<<dim3(NB, 4), 256, 0, stream>>>(w_art, a_Vw, a_Vb, aq);
    // option attention
    proj_kernel<<<dim3(NB, 4), 256, 0, stream>>>(aq, d_Qw, d_Qb, qp_d);
    score_kernel<<<dim3((NB * 5 * LO) / BM, HDIM / BN), 256, 0, stream>>>(
        options, d_Kw, d_Kb, qp_d, d_vw, s_opt, 5 * LO);
    softmax_kernel<<<NB * 5, 256, 0, stream>>>(s_opt, LO);
    wsum_kernel<<<dim3(NB * 5 * 4, 1), 256, 0, stream>>>(options, s_opt, wd, LO, LO);
    proj_kernel<<<dim3(NB * 5, 4), 256, 0, stream>>>(wd, d_Vw, d_Vb, feats);
    final_kernel<<<NB, 256, 0, stream>>>(feats, f_w, f_b, out);
}

// Round 2
// 651.692 us; speedup vs baseline: 3.5799x; 3.5799x over previous
//
#include <hip/hip_runtime.h>
#include <hip/hip_bf16.h>
#include <math.h>

#define HDIM 1024
#define NB 32
#define LA 2048
#define LO 32

typedef __attribute__((ext_vector_type(8))) short bf16x8;
typedef __attribute__((ext_vector_type(4))) float f32x4;
typedef unsigned int u32;

__device__ __forceinline__ float tanh_fast(float x){
    return 2.0f / (1.0f + __expf(-2.0f * x)) - 1.0f;
}

__device__ __forceinline__ void load_lds16(const void* gptr, void* lptr){
    __builtin_amdgcn_global_load_lds(
        (const __attribute__((address_space(1))) u32*)gptr,
        (__attribute__((address_space(3))) u32*)lptr, 16, 0, 0);
}

__global__ void zero_kernel(float* __restrict__ p, int n){
    int i = blockIdx.x * blockDim.x + threadIdx.x;
    int stride = gridDim.x * blockDim.x;
    for (; i < n; i += stride) p[i] = 0.0f;
}

__global__ void conv_bf16_kernel(const float* __restrict__ in, __hip_bfloat16* __restrict__ out, long n){
    long i = ((long)blockIdx.x * blockDim.x + threadIdx.x) * 4;
    long stride = (long)gridDim.x * blockDim.x * 4;
    for (; i < n; i += stride){
        float4 v = *(const float4*)(in + i);
        union { __hip_bfloat16 h[4]; short4 s; } u;
        u.h[0] = __float2bfloat16(v.x); u.h[1] = __float2bfloat16(v.y);
        u.h[2] = __float2bfloat16(v.z); u.h[3] = __float2bfloat16(v.w);
        *(short4*)(out + i) = u.s;
    }
}

__global__ void gather_kernel(const float* __restrict__ qc, const int* __restrict__ ans,
                              float* __restrict__ oqc){
    int b = blockIdx.x, tid = threadIdx.x;
    int idx = ans[b];
    const float* src = qc + ((size_t)b * 64 + idx) * HDIM;
    float* dst = oqc + (size_t)b * HDIM;
    #pragma unroll
    for (int l = 0; l < 4; l++) dst[tid + l * 256] = src[tid + l * 256];
}

// out[g,h] = bias[h] + dot(in[g,:], W[h,:])   grid (G, 4), block 256
__global__ void proj_kernel(const float* __restrict__ in, const float* __restrict__ W,
                            const float* __restrict__ bias, float* __restrict__ out){
    __shared__ float xin[HDIM];
    int g = blockIdx.x, tid = threadIdx.x;
    #pragma unroll
    for (int l = 0; l < 4; l++) xin[tid + l * 256] = in[(size_t)g * HDIM + tid + l * 256];
    __syncthreads();
    int h = blockIdx.y * 256 + tid;
    float acc = bias[h];
    const float* Wr = W + (size_t)h * HDIM;
    for (int k = 0; k < HDIM; k += 4){
        float4 wv = *(const float4*)&Wr[k];
        acc += xin[k] * wv.x + xin[k+1] * wv.y + xin[k+2] * wv.z + xin[k+3] * wv.w;
    }
    out[(size_t)g * HDIM + h] = acc;
}

// MFMA score kernel: s[row_off + r] += sum_h tanh(dot(X[r],Kw[h]) + Kb[h] + Qp[b][h]) * vw[h]
// X: chunk of rows (bf16, K-major), Kw: 1024x1024 bf16 (K-major). Tile 128x128, BK=32, 4 waves.
#define SBM 128
#define SBN 128
#define SBK 32
__global__ __launch_bounds__(256) void score_mfma_kernel(
    const __hip_bfloat16* __restrict__ X, const __hip_bfloat16* __restrict__ Kw,
    const float* __restrict__ Kb, const float* __restrict__ Qp,
    const float* __restrict__ vw, float* __restrict__ s,
    int row_off, int rows_per_batch)
{
    __shared__ __align__(16) __hip_bfloat16 As[SBM][SBK];  // 8 KB
    __shared__ __align__(16) __hip_bfloat16 Bs[SBN][SBK];  // 8 KB
    const int tid = threadIdx.x;
    const int lane = tid & 63, wid = tid >> 6;
    const int wm = wid >> 1, wn = wid & 1;
    const int row0 = blockIdx.x * SBM;
    const int h0 = blockIdx.y * SBN;
    const int lr = lane & 15, lg = lane >> 4;

    f32x4 acc[4][4] = {};

    for (int k0 = 0; k0 < HDIM; k0 += SBK){
        #pragma unroll
        for (int l = 0; l < 2; l++){
            int f = tid + l * 256;
            int r = f >> 2, c8 = (f & 3) * 8;
            load_lds16(X + (size_t)(row0 + r) * HDIM + k0 + c8, &As[0][0] + f * 8);
            load_lds16(Kw + (size_t)(h0 + r) * HDIM + k0 + c8, &Bs[0][0] + f * 8);
        }
        __syncthreads();
        bf16x8 a[4], b[4];
        #pragma unroll
        for (int i = 0; i < 4; i++)
            a[i] = *(const bf16x8*)&As[wm * 64 + i * 16 + lr][lg * 8];
        #pragma unroll
        for (int j = 0; j < 4; j++)
            b[j] = *(const bf16x8*)&Bs[wn * 64 + j * 16 + lr][lg * 8];
        #pragma unroll
        for (int i = 0; i < 4; i++)
            #pragma unroll
            for (int j = 0; j < 4; j++)
                acc[i][j] = __builtin_amdgcn_mfma_f32_16x16x32_bf16(a[i], b[j], acc[i][j], 0, 0, 0);
        __syncthreads();
    }

    // epilogue: tanh + vw-dot over this block's h range, reduce cols, atomicAdd per row
    float kbv[4], vwv[4];
    #pragma unroll
    for (int j = 0; j < 4; j++){
        int h = h0 + wn * 64 + j * 16 + lr;
        kbv[j] = Kb[h]; vwv[j] = vw[h];
    }
    #pragma unroll
    for (int i = 0; i < 4; i++){
        #pragma unroll
        for (int reg = 0; reg < 4; reg++){
            int r = row0 + wm * 64 + i * 16 + lg * 4 + reg;
            int gr = row_off + r;
            int b = gr / rows_per_batch;
            const float* Qpb = Qp + (size_t)b * HDIM;
            float p = 0.f;
            #pragma unroll
            for (int j = 0; j < 4; j++){
                int h = h0 + wn * 64 + j * 16 + lr;
                p += tanh_fast(acc[i][j][reg] + kbv[j] + Qpb[h]) * vwv[j];
            }
            #pragma unroll
            for (int off = 1; off < 16; off <<= 1) p += __shfl_xor(p, off, 16);
            if (lr == 0) atomicAdd(&s[gr], p);
        }
    }
}

// in-place softmax over groups of Rg, grid = G blocks of 256
__global__ void softmax_kernel(float* __restrict__ s, int Rg){
    __shared__ float red[4];
    int g = blockIdx.x, tid = threadIdx.x;
    float* sg = s + (size_t)g * Rg;
    float m = -INFINITY;
    for (int i = tid; i < Rg; i += 256) m = fmaxf(m, sg[i]);
    #pragma unroll
    for (int off = 32; off > 0; off >>= 1) m = fmaxf(m, __shfl_down(m, off, 64));
    if ((tid & 63) == 0) red[tid >> 6] = m;
    __syncthreads();
    m = fmaxf(fmaxf(red[0], red[1]), fmaxf(red[2], red[3]));
    __syncthreads();
    float sum = 0.f;
    for (int i = tid; i < Rg; i += 256){ float e = __expf(sg[i] - m); sg[i] = e; sum += e; }
    #pragma unroll
    for (int off = 32; off > 0; off >>= 1) sum += __shfl_down(sum, off, 64);
    if ((tid & 63) == 0) red[tid >> 6] = sum;
    __syncthreads();
    float inv = 1.0f / (red[0] + red[1] + red[2] + red[3]);
    for (int i = tid; i < Rg; i += 256) sg[i] *= inv;
}

// out[g,k] += sum_i sc[g,i0+i] * X[g, i0+i, k]  grid (G*4, ichunks), block 256
__global__ void wsum_kernel(const float* __restrict__ X, const float* __restrict__ sc,
                            float* __restrict__ out, int Rg, int rowsPerChunk){
    __shared__ float scs[256];
    int g = blockIdx.x >> 2;
    int kc = blockIdx.x & 3;
    int i0 = blockIdx.y * rowsPerChunk;
    int tid = threadIdx.x;
    if (tid < rowsPerChunk) scs[tid] = sc[(size_t)g * Rg + i0 + tid];
    __syncthreads();
    int k = kc * 256 + tid;
    const float* Xg = X + ((size_t)g * Rg + i0) * HDIM + k;
    float acc = 0.f;
    for (int i = 0; i < rowsPerChunk; i++)
        acc += scs[i] * Xg[(size_t)i * HDIM];
    atomicAdd(&out[(size_t)g * HDIM + k], acc);
}

// logits[b,j] = fb[j] + dot(feats[b,:5120], fw[j,:5120])  grid 32, block 256
__global__ void final_kernel(const float* __restrict__ feats, const float* __restrict__ fw,
                             const float* __restrict__ fb, float* __restrict__ out){
    __shared__ float red[4];
    int b = blockIdx.x, tid = threadIdx.x;
    const float* fe = feats + (size_t)b * 5120;
    for (int j = 0; j < 5; j++){
        float acc = 0.f;
        for (int i = tid; i < 5120; i += 256) acc += fe[i] * fw[(size_t)j * 5120 + i];
        #pragma unroll
        for (int off = 32; off > 0; off >>= 1) acc += __shfl_down(acc, off, 64);
        if ((tid & 63) == 0) red[tid >> 6] = acc;
        __syncthreads();
        if (tid == 0) out[b * 5 + j] = fb[j] + red[0] + red[1] + red[2] + red[3];
        __syncthreads();
    }
}

extern "C" void kernel_launch(void* const* d_in, const int* in_sizes, int n_in,
                              void* d_out, int out_size, void* d_ws, size_t ws_size,
                              hipStream_t stream) {
    const float* article  = (const float*)d_in[0];
    const float* question = (const float*)d_in[1];
    const float* options  = (const float*)d_in[2];
    const int*   ans      = (const int*)d_in[3];
    const float* a_Qw = (const float*)d_in[4];  const float* a_Qb = (const float*)d_in[5];
    const float* a_Kw = (const float*)d_in[6];  const float* a_Kb = (const float*)d_in[7];
    const float* a_Vw = (const float*)d_in[8];  const float* a_Vb = (const float*)d_in[9];
    const float* a_vw = (const float*)d_in[10];
    const float* d_Qw = (const float*)d_in[12]; const float* d_Qb = (const float*)d_in[13];
    const float* d_Kw = (const float*)d_in[14]; const float* d_Kb = (const float*)d_in[15];
    const float* d_Vw = (const float*)d_in[16]; const float* d_Vb = (const float*)d_in[17];
    const float* d_vw = (const float*)d_in[18];
    const float* f_w  = (const float*)d_in[20]; const float* f_b  = (const float*)d_in[21];
    float* out = (float*)d_out;

    float* ws = (float*)d_ws;
    float* oqc   = ws;               // 32768
    float* qp_a  = ws + 32768;       // 32768
    float* aq    = ws + 65536;       // 32768
    float* qp_d  = ws + 98304;       // 32768
    float* feats = ws + 131072;      // 163840
    float* s_art = ws + 294912;      // 65536  (zeroed)
    float* s_opt = ws + 360448;      // 5120   (zeroed)
    float* w_art = ws + 365568;      // 32768  (zeroed)
    float* wd    = ws + 398336;      // 163840 (zeroed)
    // bf16 region
    __hip_bfloat16* kwa_bf = (__hip_bfloat16*)(ws + 562176);
    __hip_bfloat16* kwd_bf = kwa_bf + 1048576;
    __hip_bfloat16* opt_bf = kwd_bf + 1048576;       // 5242880 elems
    __hip_bfloat16* art_bf = opt_bf + 5242880;
    size_t used_bytes = 562176 * 4 + (size_t)(1048576 * 2 + 5242880) * 2;
    long avail_rows = (long)((ws_size - used_bytes) / (HDIM * 2));
    int rows_total = NB * LA;  // 65536
    int chunk_rows = (int)(avail_rows < rows_total ? avail_rows : rows_total);
    chunk_rows &= ~127;
    if (chunk_rows < 128) chunk_rows = 128;  // trust ws_size is at least modest

    zero_kernel<<<256, 256, 0, stream>>>(s_art, 267264);
    gather_kernel<<<NB, 256, 0, stream>>>(question, ans, oqc);
    proj_kernel<<<dim3(NB, 4), 256, 0, stream>>>(oqc, a_Qw, a_Qb, qp_a);
    conv_bf16_kernel<<<64, 256, 0, stream>>>(a_Kw, kwa_bf, 1048576);

    for (int r0 = 0; r0 < rows_total; r0 += chunk_rows){
        int nr = rows_total - r0; if (nr > chunk_rows) nr = chunk_rows;
        conv_bf16_kernel<<<1024, 256, 0, stream>>>(article + (size_t)r0 * HDIM, art_bf, (long)nr * HDIM);
        score_mfma_kernel<<<dim3(nr / SBM, HDIM / SBN), 256, 0, stream>>>(
            art_bf, kwa_bf, a_Kb, qp_a, a_vw, s_art, r0, LA);
    }
    softmax_kernel<<<NB, 256, 0, stream>>>(s_art, LA);
    wsum_kernel<<<dim3(NB * 4, 8), 256, 0, stream>>>(article, s_art, w_art, LA, 256);
    proj_kernel<<<dim3(NB, 4), 256, 0, stream>>>(w_art, a_Vw, a_Vb, aq);

    proj_kernel<<<dim3(NB, 4), 256, 0, stream>>>(aq, d_Qw, d_Qb, qp_d);
    conv_bf16_kernel<<<64, 256, 0, stream>>>(d_Kw, kwd_bf, 1048576);
    conv_bf16_kernel<<<320, 256, 0, stream>>>(options, opt_bf, 5242880);
    score_mfma_kernel<<<dim3((NB * 5 * LO) / SBM, HDIM / SBN), 256, 0, stream>>>(
        opt_bf, kwd_bf, d_Kb, qp_d, d_vw, s_opt, 0, 5 * LO);
    softmax_kernel<<<NB * 5, 256, 0, stream>>>(s_opt, LO);
    wsum_kernel<<<dim3(NB * 5 * 4, 1), 256, 0, stream>>>(options, s_opt, wd, LO, LO);
    proj_kernel<<<dim3(NB * 5, 4), 256, 0, stream>>>(wd, d_Vw, d_Vb, feats);
    final_kernel<<<NB, 256, 0, stream>>>(feats, f_w, f_b, out);
}

// Round 3
// 554.024 us; speedup vs baseline: 4.2110x; 1.1763x over previous
//
#include <hip/hip_runtime.h>
#include <hip/hip_bf16.h>
#include <math.h>

#define HDIM 1024
#define NB 32
#define LA 2048
#define LO 32

typedef __attribute__((ext_vector_type(8))) short bf16x8;
typedef __attribute__((ext_vector_type(4))) float f32x4;
typedef unsigned int u32;

__device__ __forceinline__ float tanh_fast(float x){
    return 2.0f / (1.0f + __expf(-2.0f * x)) - 1.0f;
}

__device__ __forceinline__ void load_lds16(const void* gptr, void* lptr){
    __builtin_amdgcn_global_load_lds(
        (const __attribute__((address_space(1))) u32*)gptr,
        (__attribute__((address_space(3))) u32*)lptr, 16, 0, 0);
}

__global__ void zero_kernel(float* __restrict__ p, int n){
    int i = blockIdx.x * blockDim.x + threadIdx.x;
    int stride = gridDim.x * blockDim.x;
    for (; i < n; i += stride) p[i] = 0.0f;
}

__global__ void conv_bf16_kernel(const float* __restrict__ in, __hip_bfloat16* __restrict__ out, long n){
    long i = ((long)blockIdx.x * blockDim.x + threadIdx.x) * 4;
    long stride = (long)gridDim.x * blockDim.x * 4;
    for (; i < n; i += stride){
        float4 v = *(const float4*)(in + i);
        union { __hip_bfloat16 h[4]; short4 s; } u;
        u.h[0] = __float2bfloat16(v.x); u.h[1] = __float2bfloat16(v.y);
        u.h[2] = __float2bfloat16(v.z); u.h[3] = __float2bfloat16(v.w);
        *(short4*)(out + i) = u.s;
    }
}

__global__ void gather_kernel(const float* __restrict__ qc, const int* __restrict__ ans,
                              float* __restrict__ oqc){
    int b = blockIdx.x, tid = threadIdx.x;
    int idx = ans[b];
    const float* src = qc + ((size_t)b * 64 + idx) * HDIM;
    float* dst = oqc + (size_t)b * HDIM;
    #pragma unroll
    for (int l = 0; l < 4; l++) dst[tid + l * 256] = src[tid + l * 256];
}

// out[g,h] = bias[h] + dot(in[g,:], W[h,:])   grid (G, 4), block 256
__global__ void proj_kernel(const float* __restrict__ in, const float* __restrict__ W,
                            const float* __restrict__ bias, float* __restrict__ out){
    __shared__ float xin[HDIM];
    int g = blockIdx.x, tid = threadIdx.x;
    #pragma unroll
    for (int l = 0; l < 4; l++) xin[tid + l * 256] = in[(size_t)g * HDIM + tid + l * 256];
    __syncthreads();
    int h = blockIdx.y * 256 + tid;
    float acc = bias[h];
    const float* Wr = W + (size_t)h * HDIM;
    for (int k = 0; k < HDIM; k += 4){
        float4 wv = *(const float4*)&Wr[k];
        acc += xin[k] * wv.x + xin[k+1] * wv.y + xin[k+2] * wv.z + xin[k+3] * wv.w;
    }
    out[(size_t)g * HDIM + h] = acc;
}

// ---------------- 256x256 deep-pipelined article score kernel -----------------
// C[h, article] = Kw-frags (A) x article-frags (B). 8 waves (2 h-halves x 4 article
// quarters), wave tile 128h x 64a. BK=64, 2-buffer counted-vmcnt pipeline.
#define NT 16   // K tiles = 1024/64
__global__ __launch_bounds__(512, 2) void score_mfma256_kernel(
    const __hip_bfloat16* __restrict__ X, const __hip_bfloat16* __restrict__ Kw,
    const float* __restrict__ Kb, const float* __restrict__ Qp,
    const float* __restrict__ vw, float* __restrict__ s,
    int row_off, int rows_per_batch)
{
    // A (Kw tiles): 2 bufs x 32KB at offset 0; B (article): 2 bufs x 32KB at 65536
    __shared__ __align__(16) char lds[131072];
    const int tid = threadIdx.x;
    const int lane = tid & 63, wid = tid >> 6;
    const int wm = wid >> 2, wn = wid & 3;
    const int lr = lane & 15, lg = lane >> 4;
    const int a0 = blockIdx.x * 256;   // article row base (within chunk)
    const int h0 = blockIdx.y * 256;   // h base

    f32x4 acc[8][4] = {};

    const char* kwb = (const char*)Kw;
    const char* xb  = (const char*)X;

#define STAGE(kt, buf) do { \
    _Pragma("unroll") \
    for (int c = 0; c < 4; c++){ \
        int Lb = (tid + c * 512) * 16; \
        int rw = Lb >> 7, cb = Lb & 127; \
        int srcb = cb ^ ((rw & 7) << 4); \
        load_lds16(kwb + (size_t)(h0 + rw) * 2048 + (kt) * 128 + srcb, \
                   lds + (buf) * 32768 + Lb); \
    } \
    _Pragma("unroll") \
    for (int c = 0; c < 4; c++){ \
        int Lb = (tid + c * 512) * 16; \
        int rw = Lb >> 7, cb = Lb & 127; \
        int srcb = cb ^ ((rw & 7) << 4); \
        load_lds16(xb + (size_t)(a0 + rw) * 2048 + (kt) * 128 + srcb, \
                   lds + 65536 + (buf) * 32768 + Lb); \
    } } while(0)

#define COMPUTE(buf) do { \
    _Pragma("unroll") \
    for (int ks = 0; ks < 2; ks++){ \
        bf16x8 av[8], bv[4]; \
        _Pragma("unroll") \
        for (int hf = 0; hf < 8; hf++){ \
            int rw = wm * 128 + hf * 16 + lr; \
            int kb2 = ks * 64 + lg * 16; \
            av[hf] = *(const bf16x8*)(lds + (buf) * 32768 + rw * 128 + (kb2 ^ ((rw & 7) << 4))); \
        } \
        _Pragma("unroll") \
        for (int af = 0; af < 4; af++){ \
            int rw = wn * 64 + af * 16 + lr; \
            int kb2 = ks * 64 + lg * 16; \
            bv[af] = *(const bf16x8*)(lds + 65536 + (buf) * 32768 + rw * 128 + (kb2 ^ ((rw & 7) << 4))); \
        } \
        __builtin_amdgcn_s_setprio(1); \
        _Pragma("unroll") \
        for (int hf = 0; hf < 8; hf++) \
            _Pragma("unroll") \
            for (int af = 0; af < 4; af++) \
                acc[hf][af] = __builtin_amdgcn_mfma_f32_16x16x32_bf16(av[hf], bv[af], acc[hf][af], 0, 0, 0); \
        __builtin_amdgcn_s_setprio(0); \
    } } while(0)

    STAGE(0, 0);
    STAGE(1, 1);
    for (int kt = 0; kt < NT - 1; ++kt){
        asm volatile("s_waitcnt vmcnt(8)" ::: "memory");
        __builtin_amdgcn_s_barrier();
        __builtin_amdgcn_sched_barrier(0);
        COMPUTE(kt & 1);
        __builtin_amdgcn_s_barrier();
        if (kt < NT - 2) STAGE(kt + 2, kt & 1);
    }
    asm volatile("s_waitcnt vmcnt(0)" ::: "memory");
    __builtin_amdgcn_s_barrier();
    __builtin_amdgcn_sched_barrier(0);
    COMPUTE((NT - 1) & 1);

    // epilogue: per-lane h-values are rows (lg*4+reg within 16-frag); article cols = lr
    const int b = (row_off + a0) / rows_per_batch;  // uniform: 256 | rows_per_batch boundary spacing
    float qv[8][4], vv[8][4];
    #pragma unroll
    for (int hf = 0; hf < 8; hf++){
        int hbase = h0 + wm * 128 + hf * 16 + lg * 4;
        float4 kb4 = *(const float4*)(Kb + hbase);
        float4 qp4 = *(const float4*)(Qp + (size_t)b * HDIM + hbase);
        float4 vw4 = *(const float4*)(vw + hbase);
        qv[hf][0] = kb4.x + qp4.x; qv[hf][1] = kb4.y + qp4.y;
        qv[hf][2] = kb4.z + qp4.z; qv[hf][3] = kb4.w + qp4.w;
        vv[hf][0] = vw4.x; vv[hf][1] = vw4.y; vv[hf][2] = vw4.z; vv[hf][3] = vw4.w;
    }
    #pragma unroll
    for (int af = 0; af < 4; af++){
        float sacc = 0.f;
        #pragma unroll
        for (int hf = 0; hf < 8; hf++)
            #pragma unroll
            for (int r = 0; r < 4; r++)
                sacc += tanh_fast(acc[hf][af][r] + qv[hf][r]) * vv[hf][r];
        sacc += __shfl_xor(sacc, 16, 64);
        sacc += __shfl_xor(sacc, 32, 64);
        if (lane < 16)
            atomicAdd(&s[row_off + a0 + wn * 64 + af * 16 + lr], sacc);
    }
#undef STAGE
#undef COMPUTE
}

// ---------------- old 128x128 score kernel (kept for the option path) --------
#define SBM 128
#define SBN 128
__global__ __launch_bounds__(256) void score_mfma_kernel(
    const __hip_bfloat16* __restrict__ X, const __hip_bfloat16* __restrict__ Kw,
    const float* __restrict__ Kb, const float* __restrict__ Qp,
    const float* __restrict__ vw, float* __restrict__ s,
    int row_off, int rows_per_batch)
{
    __shared__ __align__(16) __hip_bfloat16 As[SBM][32];
    __shared__ __align__(16) __hip_bfloat16 Bs[SBN][32];
    const int tid = threadIdx.x;
    const int lane = tid & 63, wid = tid >> 6;
    const int wm = wid >> 1, wn = wid & 1;
    const int row0 = blockIdx.x * SBM;
    const int h0 = blockIdx.y * SBN;
    const int lr = lane & 15, lg = lane >> 4;

    f32x4 acc[4][4] = {};

    for (int k0 = 0; k0 < HDIM; k0 += 32){
        #pragma unroll
        for (int l = 0; l < 2; l++){
            int f = tid + l * 256;
            int r = f >> 2, c8 = (f & 3) * 8;
            load_lds16(X + (size_t)(row0 + r) * HDIM + k0 + c8, &As[0][0] + f * 8);
            load_lds16(Kw + (size_t)(h0 + r) * HDIM + k0 + c8, &Bs[0][0] + f * 8);
        }
        __syncthreads();
        bf16x8 a[4], b[4];
        #pragma unroll
        for (int i = 0; i < 4; i++)
            a[i] = *(const bf16x8*)&As[wm * 64 + i * 16 + lr][lg * 8];
        #pragma unroll
        for (int j = 0; j < 4; j++)
            b[j] = *(const bf16x8*)&Bs[wn * 64 + j * 16 + lr][lg * 8];
        #pragma unroll
        for (int i = 0; i < 4; i++)
            #pragma unroll
            for (int j = 0; j < 4; j++)
                acc[i][j] = __builtin_amdgcn_mfma_f32_16x16x32_bf16(a[i], b[j], acc[i][j], 0, 0, 0);
        __syncthreads();
    }

    float kbv[4], vwv[4];
    #pragma unroll
    for (int j = 0; j < 4; j++){
        int h = h0 + wn * 64 + j * 16 + lr;
        kbv[j] = Kb[h]; vwv[j] = vw[h];
    }
    #pragma unroll
    for (int i = 0; i < 4; i++){
        #pragma unroll
        for (int reg = 0; reg < 4; reg++){
            int r = row0 + wm * 64 + i * 16 + lg * 4 + reg;
            int gr = row_off + r;
            int bb = gr / rows_per_batch;
            const float* Qpb = Qp + (size_t)bb * HDIM;
            float p = 0.f;
            #pragma unroll
            for (int j = 0; j < 4; j++){
                int h = h0 + wn * 64 + j * 16 + lr;
                p += tanh_fast(acc[i][j][reg] + kbv[j] + Qpb[h]) * vwv[j];
            }
            #pragma unroll
            for (int off = 1; off < 16; off <<= 1) p += __shfl_xor(p, off, 16);
            if (lr == 0) atomicAdd(&s[gr], p);
        }
    }
}

// in-place softmax over groups of Rg, grid = G blocks of 256
__global__ void softmax_kernel(float* __restrict__ s, int Rg){
    __shared__ float red[4];
    int g = blockIdx.x, tid = threadIdx.x;
    float* sg = s + (size_t)g * Rg;
    float m = -INFINITY;
    for (int i = tid; i < Rg; i += 256) m = fmaxf(m, sg[i]);
    #pragma unroll
    for (int off = 32; off > 0; off >>= 1) m = fmaxf(m, __shfl_down(m, off, 64));
    if ((tid & 63) == 0) red[tid >> 6] = m;
    __syncthreads();
    m = fmaxf(fmaxf(red[0], red[1]), fmaxf(red[2], red[3]));
    __syncthreads();
    float sum = 0.f;
    for (int i = tid; i < Rg; i += 256){ float e = __expf(sg[i] - m); sg[i] = e; sum += e; }
    #pragma unroll
    for (int off = 32; off > 0; off >>= 1) sum += __shfl_down(sum, off, 64);
    if ((tid & 63) == 0) red[tid >> 6] = sum;
    __syncthreads();
    float inv = 1.0f / (red[0] + red[1] + red[2] + red[3]);
    for (int i = tid; i < Rg; i += 256) sg[i] *= inv;
}

// f32 weighted sum (options / fallback)
__global__ void wsum_kernel(const float* __restrict__ X, const float* __restrict__ sc,
                            float* __restrict__ out, int Rg, int rowsPerChunk){
    __shared__ float scs[256];
    int g = blockIdx.x >> 2;
    int kc = blockIdx.x & 3;
    int i0 = blockIdx.y * rowsPerChunk;
    int tid = threadIdx.x;
    if (tid < rowsPerChunk) scs[tid] = sc[(size_t)g * Rg + i0 + tid];
    __syncthreads();
    int k = kc * 256 + tid;
    const float* Xg = X + ((size_t)g * Rg + i0) * HDIM + k;
    float acc = 0.f;
    for (int i = 0; i < rowsPerChunk; i++)
        acc += scs[i] * Xg[(size_t)i * HDIM];
    atomicAdd(&out[(size_t)g * HDIM + k], acc);
}

// bf16-input weighted sum (article)
__global__ void wsum_bf16_kernel(const __hip_bfloat16* __restrict__ X, const float* __restrict__ sc,
                                 float* __restrict__ out, int Rg, int rowsPerChunk){
    __shared__ float scs[256];
    int g = blockIdx.x >> 2;
    int kc = blockIdx.x & 3;
    int i0 = blockIdx.y * rowsPerChunk;
    int tid = threadIdx.x;
    if (tid < rowsPerChunk) scs[tid] = sc[(size_t)g * Rg + i0 + tid];
    __syncthreads();
    int k = kc * 256 + tid;
    const __hip_bfloat16* Xg = X + ((size_t)g * Rg + i0) * HDIM + k;
    float acc = 0.f;
    for (int i = 0; i < rowsPerChunk; i++)
        acc += scs[i] * __bfloat162float(Xg[(size_t)i * HDIM]);
    atomicAdd(&out[(size_t)g * HDIM + k], acc);
}

// logits[b,j] = fb[j] + dot(feats[b,:5120], fw[j,:5120])  grid 32, block 256
__global__ void final_kernel(const float* __restrict__ feats, const float* __restrict__ fw,
                             const float* __restrict__ fb, float* __restrict__ out){
    __shared__ float red[4];
    int b = blockIdx.x, tid = threadIdx.x;
    const float* fe = feats + (size_t)b * 5120;
    for (int j = 0; j < 5; j++){
        float acc = 0.f;
        for (int i = tid; i < 5120; i += 256) acc += fe[i] * fw[(size_t)j * 5120 + i];
        #pragma unroll
        for (int off = 32; off > 0; off >>= 1) acc += __shfl_down(acc, off, 64);
        if ((tid & 63) == 0) red[tid >> 6] = acc;
        __syncthreads();
        if (tid == 0) out[b * 5 + j] = fb[j] + red[0] + red[1] + red[2] + red[3];
        __syncthreads();
    }
}

extern "C" void kernel_launch(void* const* d_in, const int* in_sizes, int n_in,
                              void* d_out, int out_size, void* d_ws, size_t ws_size,
                              hipStream_t stream) {
    const float* article  = (const float*)d_in[0];
    const float* question = (const float*)d_in[1];
    const float* options  = (const float*)d_in[2];
    const int*   ans      = (const int*)d_in[3];
    const float* a_Qw = (const float*)d_in[4];  const float* a_Qb = (const float*)d_in[5];
    const float* a_Kw = (const float*)d_in[6];  const float* a_Kb = (const float*)d_in[7];
    const float* a_Vw = (const float*)d_in[8];  const float* a_Vb = (const float*)d_in[9];
    const float* a_vw = (const float*)d_in[10];
    const float* d_Qw = (const float*)d_in[12]; const float* d_Qb = (const float*)d_in[13];
    const float* d_Kw = (const float*)d_in[14]; const float* d_Kb = (const float*)d_in[15];
    const float* d_Vw = (const float*)d_in[16]; const float* d_Vb = (const float*)d_in[17];
    const float* d_vw = (const float*)d_in[18];
    const float* f_w  = (const float*)d_in[20]; const float* f_b  = (const float*)d_in[21];
    float* out = (float*)d_out;

    float* ws = (float*)d_ws;
    float* oqc   = ws;               // 32768
    float* qp_a  = ws + 32768;       // 32768
    float* aq    = ws + 65536;       // 32768
    float* qp_d  = ws + 98304;       // 32768
    float* feats = ws + 131072;      // 163840
    float* s_art = ws + 294912;      // 65536  (zeroed)
    float* s_opt = ws + 360448;      // 5120   (zeroed)
    float* w_art = ws + 365568;      // 32768  (zeroed)
    float* wd    = ws + 398336;      // 163840 (zeroed)
    // bf16 region
    __hip_bfloat16* kwa_bf = (__hip_bfloat16*)(ws + 562176);
    __hip_bfloat16* kwd_bf = kwa_bf + 1048576;
    __hip_bfloat16* opt_bf = kwd_bf + 1048576;       // 5242880 elems
    __hip_bfloat16* art_bf = opt_bf + 5242880;
    size_t used_bytes = 562176 * 4 + (size_t)(1048576 * 2 + 5242880) * 2;
    long avail_rows = (long)((ws_size - used_bytes) / (HDIM * 2));
    int rows_total = NB * LA;  // 65536
    int chunk_rows = (int)(avail_rows < rows_total ? avail_rows : rows_total);
    chunk_rows &= ~255;
    if (chunk_rows < 256) chunk_rows = 256;

    zero_kernel<<<256, 256, 0, stream>>>(s_art, 267264);
    gather_kernel<<<NB, 256, 0, stream>>>(question, ans, oqc);
    proj_kernel<<<dim3(NB, 4), 256, 0, stream>>>(oqc, a_Qw, a_Qb, qp_a);
    conv_bf16_kernel<<<64, 256, 0, stream>>>(a_Kw, kwa_bf, 1048576);

    for (int r0 = 0; r0 < rows_total; r0 += chunk_rows){
        int nr = rows_total - r0; if (nr > chunk_rows) nr = chunk_rows;
        conv_bf16_kernel<<<1024, 256, 0, stream>>>(article + (size_t)r0 * HDIM, art_bf, (long)nr * HDIM);
        score_mfma256_kernel<<<dim3(nr / 256, 4), 512, 0, stream>>>(
            art_bf, kwa_bf, a_Kb, qp_a, a_vw, s_art, r0, LA);
    }
    softmax_kernel<<<NB, 256, 0, stream>>>(s_art, LA);
    if (chunk_rows >= rows_total)
        wsum_bf16_kernel<<<dim3(NB * 4, 8), 256, 0, stream>>>(art_bf, s_art, w_art, LA, 256);
    else
        wsum_kernel<<<dim3(NB * 4, 8), 256, 0, stream>>>(article, s_art, w_art, LA, 256);
    proj_kernel<<<dim3(NB, 4), 256, 0, stream>>>(w_art, a_Vw, a_Vb, aq);

    proj_kernel<<<dim3(NB, 4), 256, 0, stream>>>(aq, d_Qw, d_Qb, qp_d);
    conv_bf16_kernel<<<64, 256, 0, stream>>>(d_Kw, kwd_bf, 1048576);
    conv_bf16_kernel<<<320, 256, 0, stream>>>(options, opt_bf, 5242880);
    score_mfma_kernel<<<dim3((NB * 5 * LO) / SBM, HDIM / SBN), 256, 0, stream>>>(
        opt_bf, kwd_bf, d_Kb, qp_d, d_vw, s_opt, 0, 5 * LO);
    softmax_kernel<<<NB * 5, 256, 0, stream>>>(s_opt, LO);
    wsum_kernel<<<dim3(NB * 5 * 4, 1), 256, 0, stream>>>(options, s_opt, wd, LO, LO);
    proj_kernel<<<dim3(NB * 5, 4), 256, 0, stream>>>(wd, d_Vw, d_Vb, feats);
    final_kernel<<<NB, 256, 0, stream>>>(feats, f_w, f_b, out);
}

// Round 4
// 549.745 us; speedup vs baseline: 4.2438x; 1.0078x over previous
//
#include <hip/hip_runtime.h>
#include <hip/hip_bf16.h>
#include <math.h>

#define HDIM 1024
#define NB 32
#define LA 2048
#define LO 32

typedef __attribute__((ext_vector_type(8))) short bf16x8;
typedef __attribute__((ext_vector_type(4))) float f32x4;
typedef unsigned int u32;

__device__ __forceinline__ float tanh_fast(float x){
    return 2.0f / (1.0f + __expf(-2.0f * x)) - 1.0f;
}

__device__ __forceinline__ void load_lds16(const void* gptr, void* lptr){
    __builtin_amdgcn_global_load_lds(
        (const __attribute__((address_space(1))) u32*)gptr,
        (__attribute__((address_space(3))) u32*)lptr, 16, 0, 0);
}

__global__ void zero_kernel(float* __restrict__ p, int n){
    int i = blockIdx.x * blockDim.x + threadIdx.x;
    int stride = gridDim.x * blockDim.x;
    for (; i < n; i += stride) p[i] = 0.0f;
}

__global__ void conv_bf16_kernel(const float* __restrict__ in, __hip_bfloat16* __restrict__ out, long n){
    long i = ((long)blockIdx.x * blockDim.x + threadIdx.x) * 4;
    long stride = (long)gridDim.x * blockDim.x * 4;
    for (; i < n; i += stride){
        float4 v = *(const float4*)(in + i);
        union { __hip_bfloat16 h[4]; short4 s; } u;
        u.h[0] = __float2bfloat16(v.x); u.h[1] = __float2bfloat16(v.y);
        u.h[2] = __float2bfloat16(v.z); u.h[3] = __float2bfloat16(v.w);
        *(short4*)(out + i) = u.s;
    }
}

__global__ void gather_kernel(const float* __restrict__ qc, const int* __restrict__ ans,
                              float* __restrict__ oqc){
    int b = blockIdx.x, tid = threadIdx.x;
    int idx = ans[b];
    const float* src = qc + ((size_t)b * 64 + idx) * HDIM;
    float* dst = oqc + (size_t)b * HDIM;
    #pragma unroll
    for (int l = 0; l < 4; l++) dst[tid + l * 256] = src[tid + l * 256];
}

// out[g,h] = bias[h] + dot(in[g,:], W[h,:])   grid (G, 4), block 256
__global__ void proj_kernel(const float* __restrict__ in, const float* __restrict__ W,
                            const float* __restrict__ bias, float* __restrict__ out){
    __shared__ float xin[HDIM];
    int g = blockIdx.x, tid = threadIdx.x;
    #pragma unroll
    for (int l = 0; l < 4; l++) xin[tid + l * 256] = in[(size_t)g * HDIM + tid + l * 256];
    __syncthreads();
    int h = blockIdx.y * 256 + tid;
    float acc = bias[h];
    const float* Wr = W + (size_t)h * HDIM;
    for (int k = 0; k < HDIM; k += 4){
        float4 wv = *(const float4*)&Wr[k];
        acc += xin[k] * wv.x + xin[k+1] * wv.y + xin[k+2] * wv.z + xin[k+3] * wv.w;
    }
    out[(size_t)g * HDIM + h] = acc;
}

// ---------------- 128x128 deep-pipelined article score kernel -----------------
// C[h, article] = Kw (A) x article (B). 8 waves: wm=wid>>2 (2 h-halves of 64),
// wn=wid&3 (4 article quarters of 32). BK=64, 2-buffer counted-vmcnt pipeline,
// 64 KB LDS -> 2 blocks/CU.
#define NT 16   // K tiles = 1024/64
__global__ __launch_bounds__(512, 4) void score_mfma128_kernel(
    const __hip_bfloat16* __restrict__ X, const __hip_bfloat16* __restrict__ Kw,
    const float* __restrict__ Kb, const float* __restrict__ Qp,
    const float* __restrict__ vw, float* __restrict__ s,
    int row_off, int rows_per_batch)
{
    // A (Kw): 2 bufs x 16KB at 0; B (article): 2 bufs x 16KB at 32768
    __shared__ __align__(16) char lds[65536];
    const int tid = threadIdx.x;
    const int lane = tid & 63, wid = tid >> 6;
    const int wm = wid >> 2, wn = wid & 3;
    const int lr = lane & 15, lg = lane >> 4;
    const int a0 = blockIdx.x * 128;   // article row base (within chunk)
    const int h0 = blockIdx.y * 128;   // h base

    f32x4 acc[4][2] = {};

    const char* kwb = (const char*)Kw;
    const char* xb  = (const char*)X;

#define STAGE(kt, buf) do { \
    _Pragma("unroll") \
    for (int c = 0; c < 2; c++){ \
        int Lb = (tid + c * 512) * 16; \
        int rw = Lb >> 7, cb = Lb & 127; \
        int srcb = cb ^ ((rw & 7) << 4); \
        load_lds16(kwb + (size_t)(h0 + rw) * 2048 + (kt) * 128 + srcb, \
                   lds + (buf) * 16384 + Lb); \
    } \
    _Pragma("unroll") \
    for (int c = 0; c < 2; c++){ \
        int Lb = (tid + c * 512) * 16; \
        int rw = Lb >> 7, cb = Lb & 127; \
        int srcb = cb ^ ((rw & 7) << 4); \
        load_lds16(xb + (size_t)(a0 + rw) * 2048 + (kt) * 128 + srcb, \
                   lds + 32768 + (buf) * 16384 + Lb); \
    } } while(0)

#define COMPUTE(buf) do { \
    _Pragma("unroll") \
    for (int ks = 0; ks < 2; ks++){ \
        bf16x8 av[4], bv[2]; \
        _Pragma("unroll") \
        for (int hf = 0; hf < 4; hf++){ \
            int rw = wm * 64 + hf * 16 + lr; \
            int kb2 = ks * 64 + lg * 16; \
            av[hf] = *(const bf16x8*)(lds + (buf) * 16384 + rw * 128 + (kb2 ^ ((rw & 7) << 4))); \
        } \
        _Pragma("unroll") \
        for (int af = 0; af < 2; af++){ \
            int rw = wn * 32 + af * 16 + lr; \
            int kb2 = ks * 64 + lg * 16; \
            bv[af] = *(const bf16x8*)(lds + 32768 + (buf) * 16384 + rw * 128 + (kb2 ^ ((rw & 7) << 4))); \
        } \
        __builtin_amdgcn_s_setprio(1); \
        _Pragma("unroll") \
        for (int hf = 0; hf < 4; hf++) \
            _Pragma("unroll") \
            for (int af = 0; af < 2; af++) \
                acc[hf][af] = __builtin_amdgcn_mfma_f32_16x16x32_bf16(av[hf], bv[af], acc[hf][af], 0, 0, 0); \
        __builtin_amdgcn_s_setprio(0); \
    } } while(0)

    STAGE(0, 0);
    STAGE(1, 1);
    for (int kt = 0; kt < NT - 1; ++kt){
        asm volatile("s_waitcnt vmcnt(4)" ::: "memory");
        __builtin_amdgcn_s_barrier();
        __builtin_amdgcn_sched_barrier(0);
        COMPUTE(kt & 1);
        __builtin_amdgcn_s_barrier();
        if (kt < NT - 2) STAGE(kt + 2, kt & 1);
    }
    asm volatile("s_waitcnt vmcnt(0)" ::: "memory");
    __builtin_amdgcn_s_barrier();
    __builtin_amdgcn_sched_barrier(0);
    COMPUTE((NT - 1) & 1);

    // epilogue: per-lane h rows = lg*4+reg within each 16-frag; article col = lr
    const int b = (row_off + a0) / rows_per_batch;  // uniform: 128 | 2048
    float qv[4][4], vv[4][4];
    #pragma unroll
    for (int hf = 0; hf < 4; hf++){
        int hbase = h0 + wm * 64 + hf * 16 + lg * 4;
        float4 kb4 = *(const float4*)(Kb + hbase);
        float4 qp4 = *(const float4*)(Qp + (size_t)b * HDIM + hbase);
        float4 vw4 = *(const float4*)(vw + hbase);
        qv[hf][0] = kb4.x + qp4.x; qv[hf][1] = kb4.y + qp4.y;
        qv[hf][2] = kb4.z + qp4.z; qv[hf][3] = kb4.w + qp4.w;
        vv[hf][0] = vw4.x; vv[hf][1] = vw4.y; vv[hf][2] = vw4.z; vv[hf][3] = vw4.w;
    }
    #pragma unroll
    for (int af = 0; af < 2; af++){
        float sacc = 0.f;
        #pragma unroll
        for (int hf = 0; hf < 4; hf++)
            #pragma unroll
            for (int r = 0; r < 4; r++)
                sacc += tanh_fast(acc[hf][af][r] + qv[hf][r]) * vv[hf][r];
        sacc += __shfl_xor(sacc, 16, 64);
        sacc += __shfl_xor(sacc, 32, 64);
        if (lane < 16)
            atomicAdd(&s[row_off + a0 + wn * 32 + af * 16 + lr], sacc);
    }
#undef STAGE
#undef COMPUTE
}

// ---------------- old 128x128 4-wave score kernel (option path) --------------
#define SBM 128
#define SBN 128
__global__ __launch_bounds__(256) void score_mfma_kernel(
    const __hip_bfloat16* __restrict__ X, const __hip_bfloat16* __restrict__ Kw,
    const float* __restrict__ Kb, const float* __restrict__ Qp,
    const float* __restrict__ vw, float* __restrict__ s,
    int row_off, int rows_per_batch)
{
    __shared__ __align__(16) __hip_bfloat16 As[SBM][32];
    __shared__ __align__(16) __hip_bfloat16 Bs[SBN][32];
    const int tid = threadIdx.x;
    const int lane = tid & 63, wid = tid >> 6;
    const int wm = wid >> 1, wn = wid & 1;
    const int row0 = blockIdx.x * SBM;
    const int h0 = blockIdx.y * SBN;
    const int lr = lane & 15, lg = lane >> 4;

    f32x4 acc[4][4] = {};

    for (int k0 = 0; k0 < HDIM; k0 += 32){
        #pragma unroll
        for (int l = 0; l < 2; l++){
            int f = tid + l * 256;
            int r = f >> 2, c8 = (f & 3) * 8;
            load_lds16(X + (size_t)(row0 + r) * HDIM + k0 + c8, &As[0][0] + f * 8);
            load_lds16(Kw + (size_t)(h0 + r) * HDIM + k0 + c8, &Bs[0][0] + f * 8);
        }
        __syncthreads();
        bf16x8 a[4], b[4];
        #pragma unroll
        for (int i = 0; i < 4; i++)
            a[i] = *(const bf16x8*)&As[wm * 64 + i * 16 + lr][lg * 8];
        #pragma unroll
        for (int j = 0; j < 4; j++)
            b[j] = *(const bf16x8*)&Bs[wn * 64 + j * 16 + lr][lg * 8];
        #pragma unroll
        for (int i = 0; i < 4; i++)
            #pragma unroll
            for (int j = 0; j < 4; j++)
                acc[i][j] = __builtin_amdgcn_mfma_f32_16x16x32_bf16(a[i], b[j], acc[i][j], 0, 0, 0);
        __syncthreads();
    }

    float kbv[4], vwv[4];
    #pragma unroll
    for (int j = 0; j < 4; j++){
        int h = h0 + wn * 64 + j * 16 + lr;
        kbv[j] = Kb[h]; vwv[j] = vw[h];
    }
    #pragma unroll
    for (int i = 0; i < 4; i++){
        #pragma unroll
        for (int reg = 0; reg < 4; reg++){
            int r = row0 + wm * 64 + i * 16 + lg * 4 + reg;
            int gr = row_off + r;
            int bb = gr / rows_per_batch;
            const float* Qpb = Qp + (size_t)bb * HDIM;
            float p = 0.f;
            #pragma unroll
            for (int j = 0; j < 4; j++){
                int h = h0 + wn * 64 + j * 16 + lr;
                p += tanh_fast(acc[i][j][reg] + kbv[j] + Qpb[h]) * vwv[j];
            }
            #pragma unroll
            for (int off = 1; off < 16; off <<= 1) p += __shfl_xor(p, off, 16);
            if (lr == 0) atomicAdd(&s[gr], p);
        }
    }
}

// in-place softmax over groups of Rg, grid = G blocks of 256
__global__ void softmax_kernel(float* __restrict__ s, int Rg){
    __shared__ float red[4];
    int g = blockIdx.x, tid = threadIdx.x;
    float* sg = s + (size_t)g * Rg;
    float m = -INFINITY;
    for (int i = tid; i < Rg; i += 256) m = fmaxf(m, sg[i]);
    #pragma unroll
    for (int off = 32; off > 0; off >>= 1) m = fmaxf(m, __shfl_down(m, off, 64));
    if ((tid & 63) == 0) red[tid >> 6] = m;
    __syncthreads();
    m = fmaxf(fmaxf(red[0], red[1]), fmaxf(red[2], red[3]));
    __syncthreads();
    float sum = 0.f;
    for (int i = tid; i < Rg; i += 256){ float e = __expf(sg[i] - m); sg[i] = e; sum += e; }
    #pragma unroll
    for (int off = 32; off > 0; off >>= 1) sum += __shfl_down(sum, off, 64);
    if ((tid & 63) == 0) red[tid >> 6] = sum;
    __syncthreads();
    float inv = 1.0f / (red[0] + red[1] + red[2] + red[3]);
    for (int i = tid; i < Rg; i += 256) sg[i] *= inv;
}

// f32 weighted sum (options / fallback)
__global__ void wsum_kernel(const float* __restrict__ X, const float* __restrict__ sc,
                            float* __restrict__ out, int Rg, int rowsPerChunk){
    __shared__ float scs[256];
    int g = blockIdx.x >> 2;
    int kc = blockIdx.x & 3;
    int i0 = blockIdx.y * rowsPerChunk;
    int tid = threadIdx.x;
    if (tid < rowsPerChunk) scs[tid] = sc[(size_t)g * Rg + i0 + tid];
    __syncthreads();
    int k = kc * 256 + tid;
    const float* Xg = X + ((size_t)g * Rg + i0) * HDIM + k;
    float acc = 0.f;
    for (int i = 0; i < rowsPerChunk; i++)
        acc += scs[i] * Xg[(size_t)i * HDIM];
    atomicAdd(&out[(size_t)g * HDIM + k], acc);
}

// bf16-input weighted sum (article)
__global__ void wsum_bf16_kernel(const __hip_bfloat16* __restrict__ X, const float* __restrict__ sc,
                                 float* __restrict__ out, int Rg, int rowsPerChunk){
    __shared__ float scs[256];
    int g = blockIdx.x >> 2;
    int kc = blockIdx.x & 3;
    int i0 = blockIdx.y * rowsPerChunk;
    int tid = threadIdx.x;
    if (tid < rowsPerChunk) scs[tid] = sc[(size_t)g * Rg + i0 + tid];
    __syncthreads();
    int k = kc * 256 + tid;
    const __hip_bfloat16* Xg = X + ((size_t)g * Rg + i0) * HDIM + k;
    float acc = 0.f;
    for (int i = 0; i < rowsPerChunk; i++)
        acc += scs[i] * __bfloat162float(Xg[(size_t)i * HDIM]);
    atomicAdd(&out[(size_t)g * HDIM + k], acc);
}

// logits[b,j] = fb[j] + dot(feats[b,:5120], fw[j,:5120])  grid 32, block 256
__global__ void final_kernel(const float* __restrict__ feats, const float* __restrict__ fw,
                             const float* __restrict__ fb, float* __restrict__ out){
    __shared__ float red[4];
    int b = blockIdx.x, tid = threadIdx.x;
    const float* fe = feats + (size_t)b * 5120;
    for (int j = 0; j < 5; j++){
        float acc = 0.f;
        for (int i = tid; i < 5120; i += 256) acc += fe[i] * fw[(size_t)j * 5120 + i];
        #pragma unroll
        for (int off = 32; off > 0; off >>= 1) acc += __shfl_down(acc, off, 64);
        if ((tid & 63) == 0) red[tid >> 6] = acc;
        __syncthreads();
        if (tid == 0) out[b * 5 + j] = fb[j] + red[0] + red[1] + red[2] + red[3];
        __syncthreads();
    }
}

extern "C" void kernel_launch(void* const* d_in, const int* in_sizes, int n_in,
                              void* d_out, int out_size, void* d_ws, size_t ws_size,
                              hipStream_t stream) {
    const float* article  = (const float*)d_in[0];
    const float* question = (const float*)d_in[1];
    const float* options  = (const float*)d_in[2];
    const int*   ans      = (const int*)d_in[3];
    const float* a_Qw = (const float*)d_in[4];  const float* a_Qb = (const float*)d_in[5];
    const float* a_Kw = (const float*)d_in[6];  const float* a_Kb = (const float*)d_in[7];
    const float* a_Vw = (const float*)d_in[8];  const float* a_Vb = (const float*)d_in[9];
    const float* a_vw = (const float*)d_in[10];
    const float* d_Qw = (const float*)d_in[12]; const float* d_Qb = (const float*)d_in[13];
    const float* d_Kw = (const float*)d_in[14]; const float* d_Kb = (const float*)d_in[15];
    const float* d_Vw = (const float*)d_in[16]; const float* d_Vb = (const float*)d_in[17];
    const float* d_vw = (const float*)d_in[18];
    const float* f_w  = (const float*)d_in[20]; const float* f_b  = (const float*)d_in[21];
    float* out = (float*)d_out;

    float* ws = (float*)d_ws;
    float* oqc   = ws;               // 32768
    float* qp_a  = ws + 32768;       // 32768
    float* aq    = ws + 65536;       // 32768
    float* qp_d  = ws + 98304;       // 32768
    float* feats = ws + 131072;      // 163840
    float* s_art = ws + 294912;      // 65536  (zeroed)
    float* s_opt = ws + 360448;      // 5120   (zeroed)
    float* w_art = ws + 365568;      // 32768  (zeroed)
    float* wd    = ws + 398336;      // 163840 (zeroed)
    // bf16 region
    __hip_bfloat16* kwa_bf = (__hip_bfloat16*)(ws + 562176);
    __hip_bfloat16* kwd_bf = kwa_bf + 1048576;
    __hip_bfloat16* opt_bf = kwd_bf + 1048576;       // 5242880 elems
    __hip_bfloat16* art_bf = opt_bf + 5242880;
    size_t used_bytes = 562176 * 4 + (size_t)(1048576 * 2 + 5242880) * 2;
    long avail_rows = (long)((ws_size - used_bytes) / (HDIM * 2));
    int rows_total = NB * LA;  // 65536
    int chunk_rows = (int)(avail_rows < rows_total ? avail_rows : rows_total);
    chunk_rows &= ~255;
    if (chunk_rows < 256) chunk_rows = 256;

    zero_kernel<<<256, 256, 0, stream>>>(s_art, 267264);
    gather_kernel<<<NB, 256, 0, stream>>>(question, ans, oqc);
    proj_kernel<<<dim3(NB, 4), 256, 0, stream>>>(oqc, a_Qw, a_Qb, qp_a);
    conv_bf16_kernel<<<64, 256, 0, stream>>>(a_Kw, kwa_bf, 1048576);

    for (int r0 = 0; r0 < rows_total; r0 += chunk_rows){
        int nr = rows_total - r0; if (nr > chunk_rows) nr = chunk_rows;
        conv_bf16_kernel<<<1024, 256, 0, stream>>>(article + (size_t)r0 * HDIM, art_bf, (long)nr * HDIM);
        score_mfma128_kernel<<<dim3(nr / 128, 8), 512, 0, stream>>>(
            art_bf, kwa_bf, a_Kb, qp_a, a_vw, s_art, r0, LA);
    }
    softmax_kernel<<<NB, 256, 0, stream>>>(s_art, LA);
    if (chunk_rows >= rows_total)
        wsum_bf16_kernel<<<dim3(NB * 4, 8), 256, 0, stream>>>(art_bf, s_art, w_art, LA, 256);
    else
        wsum_kernel<<<dim3(NB * 4, 8), 256, 0, stream>>>(article, s_art, w_art, LA, 256);
    proj_kernel<<<dim3(NB, 4), 256, 0, stream>>>(w_art, a_Vw, a_Vb, aq);

    proj_kernel<<<dim3(NB, 4), 256, 0, stream>>>(aq, d_Qw, d_Qb, qp_d);
    conv_bf16_kernel<<<64, 256, 0, stream>>>(d_Kw, kwd_bf, 1048576);
    conv_bf16_kernel<<<320, 256, 0, stream>>>(options, opt_bf, 5242880);
    score_mfma_kernel<<<dim3((NB * 5 * LO) / SBM, HDIM / SBN), 256, 0, stream>>>(
        opt_bf, kwd_bf, d_Kb, qp_d, d_vw, s_opt, 0, 5 * LO);
    softmax_kernel<<<NB * 5, 256, 0, stream>>>(s_opt, LO);
    wsum_kernel<<<dim3(NB * 5 * 4, 1), 256, 0, stream>>>(options, s_opt, wd, LO, LO);
    proj_kernel<<<dim3(NB * 5, 4), 256, 0, stream>>>(wd, d_Vw, d_Vb, feats);
    final_kernel<<<NB, 256, 0, stream>>>(feats, f_w, f_b, out);
}

// Round 5
// 541.416 us; speedup vs baseline: 4.3091x; 1.0154x over previous
//
#include <hip/hip_runtime.h>
#include <hip/hip_bf16.h>
#include <math.h>

#define HDIM 1024
#define NB 32
#define LA 2048
#define LO 32

typedef __attribute__((ext_vector_type(8))) short bf16x8;
typedef __attribute__((ext_vector_type(4))) float f32x4;
typedef unsigned int u32;

__device__ __forceinline__ float tanh_fast(float x){
    return 2.0f / (1.0f + __expf(-2.0f * x)) - 1.0f;
}

__device__ __forceinline__ void load_lds16(const void* gptr, void* lptr){
    __builtin_amdgcn_global_load_lds(
        (const __attribute__((address_space(1))) u32*)gptr,
        (__attribute__((address_space(3))) u32*)lptr, 16, 0, 0);
}

__global__ void zero_kernel(float* __restrict__ p, int n){
    int i = blockIdx.x * blockDim.x + threadIdx.x;
    int stride = gridDim.x * blockDim.x;
    for (; i < n; i += stride) p[i] = 0.0f;
}

__global__ void conv_bf16_kernel(const float* __restrict__ in, __hip_bfloat16* __restrict__ out, long n){
    long i = ((long)blockIdx.x * blockDim.x + threadIdx.x) * 4;
    long stride = (long)gridDim.x * blockDim.x * 4;
    for (; i < n; i += stride){
        float4 v = *(const float4*)(in + i);
        union { __hip_bfloat16 h[4]; short4 s; } u;
        u.h[0] = __float2bfloat16(v.x); u.h[1] = __float2bfloat16(v.y);
        u.h[2] = __float2bfloat16(v.z); u.h[3] = __float2bfloat16(v.w);
        *(short4*)(out + i) = u.s;
    }
}

__global__ void gather_kernel(const float* __restrict__ qc, const int* __restrict__ ans,
                              float* __restrict__ oqc){
    int b = blockIdx.x, tid = threadIdx.x;
    int idx = ans[b];
    const float* src = qc + ((size_t)b * 64 + idx) * HDIM;
    float* dst = oqc + (size_t)b * HDIM;
    #pragma unroll
    for (int l = 0; l < 4; l++) dst[tid + l * 256] = src[tid + l * 256];
}

// out[g,h] = bias[h] + dot(in[g,:], W[h,:])   grid (G, 4), block 256
__global__ void proj_kernel(const float* __restrict__ in, const float* __restrict__ W,
                            const float* __restrict__ bias, float* __restrict__ out){
    __shared__ float xin[HDIM];
    int g = blockIdx.x, tid = threadIdx.x;
    #pragma unroll
    for (int l = 0; l < 4; l++) xin[tid + l * 256] = in[(size_t)g * HDIM + tid + l * 256];
    __syncthreads();
    int h = blockIdx.y * 256 + tid;
    float acc = bias[h];
    const float* Wr = W + (size_t)h * HDIM;
    for (int k = 0; k < HDIM; k += 4){
        float4 wv = *(const float4*)&Wr[k];
        acc += xin[k] * wv.x + xin[k+1] * wv.y + xin[k+2] * wv.z + xin[k+3] * wv.w;
    }
    out[(size_t)g * HDIM + h] = acc;
}

// ---------------- 128x128 deep-pipelined article score kernel -----------------
// C[h, article] = Kw (A) x article (B). 8 waves: wm (2 h-halves of 64),
// wn (4 article quarters of 32). BK=64, 2-buffer counted-vmcnt pipeline.
// 1-D grid of na*8 blocks, XCD-aware decode: blocks sharing an article tile
// run temporally adjacent on the SAME XCD (bid%8) -> article hits L2 (~4MB:
// 8-tile sliding window 2MB + full Kw 2MB).  Requires na % 8 == 0.
#define NT 16   // K tiles = 1024/64
__global__ __launch_bounds__(512, 4) void score_mfma128_kernel(
    const __hip_bfloat16* __restrict__ X, const __hip_bfloat16* __restrict__ Kw,
    const float* __restrict__ Kb, const float* __restrict__ Qp,
    const float* __restrict__ vw, float* __restrict__ s,
    int row_off, int rows_per_batch)
{
    // A (Kw): 2 bufs x 16KB at 0; B (article): 2 bufs x 16KB at 32768
    __shared__ __align__(16) char lds[65536];
    const int tid = threadIdx.x;
    const int lane = tid & 63, wid = tid >> 6;
    const int wm = wid >> 2, wn = wid & 3;
    const int lr = lane & 15, lg = lane >> 4;

    const int na = gridDim.x >> 3;          // article tiles
    const int per = na >> 3;                // a-tiles per XCD
    const int bid = blockIdx.x;
    const int xcd = bid & 7, seq = bid >> 3;
    const int a_idx = xcd * per + (seq >> 3);
    const int h_idx = seq & 7;
    const int a0 = a_idx * 128;             // article row base (within chunk)
    const int h0 = h_idx * 128;             // h base

    f32x4 acc[4][2] = {};

    const char* kwb = (const char*)Kw;
    const char* xb  = (const char*)X;

#define STAGE(kt, buf) do { \
    _Pragma("unroll") \
    for (int c = 0; c < 2; c++){ \
        int Lb = (tid + c * 512) * 16; \
        int rw = Lb >> 7, cb = Lb & 127; \
        int srcb = cb ^ ((rw & 7) << 4); \
        load_lds16(kwb + (size_t)(h0 + rw) * 2048 + (kt) * 128 + srcb, \
                   lds + (buf) * 16384 + Lb); \
    } \
    _Pragma("unroll") \
    for (int c = 0; c < 2; c++){ \
        int Lb = (tid + c * 512) * 16; \
        int rw = Lb >> 7, cb = Lb & 127; \
        int srcb = cb ^ ((rw & 7) << 4); \
        load_lds16(xb + (size_t)(a0 + rw) * 2048 + (kt) * 128 + srcb, \
                   lds + 32768 + (buf) * 16384 + Lb); \
    } } while(0)

#define COMPUTE(buf) do { \
    _Pragma("unroll") \
    for (int ks = 0; ks < 2; ks++){ \
        bf16x8 av[4], bv[2]; \
        _Pragma("unroll") \
        for (int hf = 0; hf < 4; hf++){ \
            int rw = wm * 64 + hf * 16 + lr; \
            int kb2 = ks * 64 + lg * 16; \
            av[hf] = *(const bf16x8*)(lds + (buf) * 16384 + rw * 128 + (kb2 ^ ((rw & 7) << 4))); \
        } \
        _Pragma("unroll") \
        for (int af = 0; af < 2; af++){ \
            int rw = wn * 32 + af * 16 + lr; \
            int kb2 = ks * 64 + lg * 16; \
            bv[af] = *(const bf16x8*)(lds + 32768 + (buf) * 16384 + rw * 128 + (kb2 ^ ((rw & 7) << 4))); \
        } \
        __builtin_amdgcn_s_setprio(1); \
        _Pragma("unroll") \
        for (int hf = 0; hf < 4; hf++) \
            _Pragma("unroll") \
            for (int af = 0; af < 2; af++) \
                acc[hf][af] = __builtin_amdgcn_mfma_f32_16x16x32_bf16(av[hf], bv[af], acc[hf][af], 0, 0, 0); \
        __builtin_amdgcn_s_setprio(0); \
    } } while(0)

    STAGE(0, 0);
    STAGE(1, 1);
    for (int kt = 0; kt < NT - 1; ++kt){
        asm volatile("s_waitcnt vmcnt(4)" ::: "memory");
        __builtin_amdgcn_s_barrier();
        __builtin_amdgcn_sched_barrier(0);
        COMPUTE(kt & 1);
        __builtin_amdgcn_s_barrier();
        if (kt < NT - 2) STAGE(kt + 2, kt & 1);
    }
    asm volatile("s_waitcnt vmcnt(0)" ::: "memory");
    __builtin_amdgcn_s_barrier();
    __builtin_amdgcn_sched_barrier(0);
    COMPUTE((NT - 1) & 1);

    // epilogue: per-lane h rows = lg*4+reg within each 16-frag; article col = lr
    const int b = (row_off + a0) / rows_per_batch;  // uniform: 128 | 2048
    float qv[4][4], vv[4][4];
    #pragma unroll
    for (int hf = 0; hf < 4; hf++){
        int hbase = h0 + wm * 64 + hf * 16 + lg * 4;
        float4 kb4 = *(const float4*)(Kb + hbase);
        float4 qp4 = *(const float4*)(Qp + (size_t)b * HDIM + hbase);
        float4 vw4 = *(const float4*)(vw + hbase);
        qv[hf][0] = kb4.x + qp4.x; qv[hf][1] = kb4.y + qp4.y;
        qv[hf][2] = kb4.z + qp4.z; qv[hf][3] = kb4.w + qp4.w;
        vv[hf][0] = vw4.x; vv[hf][1] = vw4.y; vv[hf][2] = vw4.z; vv[hf][3] = vw4.w;
    }
    #pragma unroll
    for (int af = 0; af < 2; af++){
        float sacc = 0.f;
        #pragma unroll
        for (int hf = 0; hf < 4; hf++)
            #pragma unroll
            for (int r = 0; r < 4; r++)
                sacc += tanh_fast(acc[hf][af][r] + qv[hf][r]) * vv[hf][r];
        sacc += __shfl_xor(sacc, 16, 64);
        sacc += __shfl_xor(sacc, 32, 64);
        if (lane < 16)
            atomicAdd(&s[row_off + a0 + wn * 32 + af * 16 + lr], sacc);
    }
#undef STAGE
#undef COMPUTE
}

// ---------------- old 128x128 4-wave score kernel (option path) --------------
#define SBM 128
#define SBN 128
__global__ __launch_bounds__(256) void score_mfma_kernel(
    const __hip_bfloat16* __restrict__ X, const __hip_bfloat16* __restrict__ Kw,
    const float* __restrict__ Kb, const float* __restrict__ Qp,
    const float* __restrict__ vw, float* __restrict__ s,
    int row_off, int rows_per_batch)
{
    __shared__ __align__(16) __hip_bfloat16 As[SBM][32];
    __shared__ __align__(16) __hip_bfloat16 Bs[SBN][32];
    const int tid = threadIdx.x;
    const int lane = tid & 63, wid = tid >> 6;
    const int wm = wid >> 1, wn = wid & 1;
    const int row0 = blockIdx.x * SBM;
    const int h0 = blockIdx.y * SBN;
    const int lr = lane & 15, lg = lane >> 4;

    f32x4 acc[4][4] = {};

    for (int k0 = 0; k0 < HDIM; k0 += 32){
        #pragma unroll
        for (int l = 0; l < 2; l++){
            int f = tid + l * 256;
            int r = f >> 2, c8 = (f & 3) * 8;
            load_lds16(X + (size_t)(row0 + r) * HDIM + k0 + c8, &As[0][0] + f * 8);
            load_lds16(Kw + (size_t)(h0 + r) * HDIM + k0 + c8, &Bs[0][0] + f * 8);
        }
        __syncthreads();
        bf16x8 a[4], b[4];
        #pragma unroll
        for (int i = 0; i < 4; i++)
            a[i] = *(const bf16x8*)&As[wm * 64 + i * 16 + lr][lg * 8];
        #pragma unroll
        for (int j = 0; j < 4; j++)
            b[j] = *(const bf16x8*)&Bs[wn * 64 + j * 16 + lr][lg * 8];
        #pragma unroll
        for (int i = 0; i < 4; i++)
            #pragma unroll
            for (int j = 0; j < 4; j++)
                acc[i][j] = __builtin_amdgcn_mfma_f32_16x16x32_bf16(a[i], b[j], acc[i][j], 0, 0, 0);
        __syncthreads();
    }

    float kbv[4], vwv[4];
    #pragma unroll
    for (int j = 0; j < 4; j++){
        int h = h0 + wn * 64 + j * 16 + lr;
        kbv[j] = Kb[h]; vwv[j] = vw[h];
    }
    #pragma unroll
    for (int i = 0; i < 4; i++){
        #pragma unroll
        for (int reg = 0; reg < 4; reg++){
            int r = row0 + wm * 64 + i * 16 + lg * 4 + reg;
            int gr = row_off + r;
            int bb = gr / rows_per_batch;
            const float* Qpb = Qp + (size_t)bb * HDIM;
            float p = 0.f;
            #pragma unroll
            for (int j = 0; j < 4; j++){
                int h = h0 + wn * 64 + j * 16 + lr;
                p += tanh_fast(acc[i][j][reg] + kbv[j] + Qpb[h]) * vwv[j];
            }
            #pragma unroll
            for (int off = 1; off < 16; off <<= 1) p += __shfl_xor(p, off, 16);
            if (lr == 0) atomicAdd(&s[gr], p);
        }
    }
}

// in-place softmax over groups of Rg, grid = G blocks of 256
__global__ void softmax_kernel(float* __restrict__ s, int Rg){
    __shared__ float red[4];
    int g = blockIdx.x, tid = threadIdx.x;
    float* sg = s + (size_t)g * Rg;
    float m = -INFINITY;
    for (int i = tid; i < Rg; i += 256) m = fmaxf(m, sg[i]);
    #pragma unroll
    for (int off = 32; off > 0; off >>= 1) m = fmaxf(m, __shfl_down(m, off, 64));
    if ((tid & 63) == 0) red[tid >> 6] = m;
    __syncthreads();
    m = fmaxf(fmaxf(red[0], red[1]), fmaxf(red[2], red[3]));
    __syncthreads();
    float sum = 0.f;
    for (int i = tid; i < Rg; i += 256){ float e = __expf(sg[i] - m); sg[i] = e; sum += e; }
    #pragma unroll
    for (int off = 32; off > 0; off >>= 1) sum += __shfl_down(sum, off, 64);
    if ((tid & 63) == 0) red[tid >> 6] = sum;
    __syncthreads();
    float inv = 1.0f / (red[0] + red[1] + red[2] + red[3]);
    for (int i = tid; i < Rg; i += 256) sg[i] *= inv;
}

// f32 weighted sum (options / fallback)
__global__ void wsum_kernel(const float* __restrict__ X, const float* __restrict__ sc,
                            float* __restrict__ out, int Rg, int rowsPerChunk){
    __shared__ float scs[256];
    int g = blockIdx.x >> 2;
    int kc = blockIdx.x & 3;
    int i0 = blockIdx.y * rowsPerChunk;
    int tid = threadIdx.x;
    if (tid < rowsPerChunk) scs[tid] = sc[(size_t)g * Rg + i0 + tid];
    __syncthreads();
    int k = kc * 256 + tid;
    const float* Xg = X + ((size_t)g * Rg + i0) * HDIM + k;
    float acc = 0.f;
    for (int i = 0; i < rowsPerChunk; i++)
        acc += scs[i] * Xg[(size_t)i * HDIM];
    atomicAdd(&out[(size_t)g * HDIM + k], acc);
}

// bf16-input weighted sum (article)
__global__ void wsum_bf16_kernel(const __hip_bfloat16* __restrict__ X, const float* __restrict__ sc,
                                 float* __restrict__ out, int Rg, int rowsPerChunk){
    __shared__ float scs[256];
    int g = blockIdx.x >> 2;
    int kc = blockIdx.x & 3;
    int i0 = blockIdx.y * rowsPerChunk;
    int tid = threadIdx.x;
    if (tid < rowsPerChunk) scs[tid] = sc[(size_t)g * Rg + i0 + tid];
    __syncthreads();
    int k = kc * 256 + tid;
    const __hip_bfloat16* Xg = X + ((size_t)g * Rg + i0) * HDIM + k;
    float acc = 0.f;
    for (int i = 0; i < rowsPerChunk; i++)
        acc += scs[i] * __bfloat162float(Xg[(size_t)i * HDIM]);
    atomicAdd(&out[(size_t)g * HDIM + k], acc);
}

// logits[b,j] = fb[j] + dot(feats[b,:5120], fw[j,:5120])  grid 32, block 256
__global__ void final_kernel(const float* __restrict__ feats, const float* __restrict__ fw,
                             const float* __restrict__ fb, float* __restrict__ out){
    __shared__ float red[4];
    int b = blockIdx.x, tid = threadIdx.x;
    const float* fe = feats + (size_t)b * 5120;
    for (int j = 0; j < 5; j++){
        float acc = 0.f;
        for (int i = tid; i < 5120; i += 256) acc += fe[i] * fw[(size_t)j * 5120 + i];
        #pragma unroll
        for (int off = 32; off > 0; off >>= 1) acc += __shfl_down(acc, off, 64);
        if ((tid & 63) == 0) red[tid >> 6] = acc;
        __syncthreads();
        if (tid == 0) out[b * 5 + j] = fb[j] + red[0] + red[1] + red[2] + red[3];
        __syncthreads();
    }
}

extern "C" void kernel_launch(void* const* d_in, const int* in_sizes, int n_in,
                              void* d_out, int out_size, void* d_ws, size_t ws_size,
                              hipStream_t stream) {
    const float* article  = (const float*)d_in[0];
    const float* question = (const float*)d_in[1];
    const float* options  = (const float*)d_in[2];
    const int*   ans      = (const int*)d_in[3];
    const float* a_Qw = (const float*)d_in[4];  const float* a_Qb = (const float*)d_in[5];
    const float* a_Kw = (const float*)d_in[6];  const float* a_Kb = (const float*)d_in[7];
    const float* a_Vw = (const float*)d_in[8];  const float* a_Vb = (const float*)d_in[9];
    const float* a_vw = (const float*)d_in[10];
    const float* d_Qw = (const float*)d_in[12]; const float* d_Qb = (const float*)d_in[13];
    const float* d_Kw = (const float*)d_in[14]; const float* d_Kb = (const float*)d_in[15];
    const float* d_Vw = (const float*)d_in[16]; const float* d_Vb = (const float*)d_in[17];
    const float* d_vw = (const float*)d_in[18];
    const float* f_w  = (const float*)d_in[20]; const float* f_b  = (const float*)d_in[21];
    float* out = (float*)d_out;

    float* ws = (float*)d_ws;
    float* oqc   = ws;               // 32768
    float* qp_a  = ws + 32768;       // 32768
    float* aq    = ws + 65536;       // 32768
    float* qp_d  = ws + 98304;       // 32768
    float* feats = ws + 131072;      // 163840
    float* s_art = ws + 294912;      // 65536  (zeroed)
    float* s_opt = ws + 360448;      // 5120   (zeroed)
    float* w_art = ws + 365568;      // 32768  (zeroed)
    float* wd    = ws + 398336;      // 163840 (zeroed)
    // bf16 region
    __hip_bfloat16* kwa_bf = (__hip_bfloat16*)(ws + 562176);
    __hip_bfloat16* kwd_bf = kwa_bf + 1048576;
    __hip_bfloat16* opt_bf = kwd_bf + 1048576;       // 5242880 elems
    __hip_bfloat16* art_bf = opt_bf + 5242880;
    size_t used_bytes = 562176 * 4 + (size_t)(1048576 * 2 + 5242880) * 2;
    long avail_rows = (long)((ws_size - used_bytes) / (HDIM * 2));
    int rows_total = NB * LA;  // 65536
    int chunk_rows = (int)(avail_rows < rows_total ? avail_rows : rows_total);
    chunk_rows &= ~1023;               // na (= chunk/128) must be a multiple of 8
    if (chunk_rows < 1024) chunk_rows = 1024;

    zero_kernel<<<256, 256, 0, stream>>>(s_art, 267264);
    gather_kernel<<<NB, 256, 0, stream>>>(question, ans, oqc);
    proj_kernel<<<dim3(NB, 4), 256, 0, stream>>>(oqc, a_Qw, a_Qb, qp_a);
    conv_bf16_kernel<<<64, 256, 0, stream>>>(a_Kw, kwa_bf, 1048576);

    for (int r0 = 0; r0 < rows_total; r0 += chunk_rows){
        int nr = rows_total - r0; if (nr > chunk_rows) nr = chunk_rows;
        conv_bf16_kernel<<<1024, 256, 0, stream>>>(article + (size_t)r0 * HDIM, art_bf, (long)nr * HDIM);
        score_mfma128_kernel<<<(nr / 128) * 8, 512, 0, stream>>>(
            art_bf, kwa_bf, a_Kb, qp_a, a_vw, s_art, r0, LA);
    }
    softmax_kernel<<<NB, 256, 0, stream>>>(s_art, LA);
    if (chunk_rows >= rows_total)
        wsum_bf16_kernel<<<dim3(NB * 4, 8), 256, 0, stream>>>(art_bf, s_art, w_art, LA, 256);
    else
        wsum_kernel<<<dim3(NB * 4, 8), 256, 0, stream>>>(article, s_art, w_art, LA, 256);
    proj_kernel<<<dim3(NB, 4), 256, 0, stream>>>(w_art, a_Vw, a_Vb, aq);

    proj_kernel<<<dim3(NB, 4), 256, 0, stream>>>(aq, d_Qw, d_Qb, qp_d);
    conv_bf16_kernel<<<64, 256, 0, stream>>>(d_Kw, kwd_bf, 1048576);
    conv_bf16_kernel<<<320, 256, 0, stream>>>(options, opt_bf, 5242880);
    score_mfma_kernel<<<dim3((NB * 5 * LO) / SBM, HDIM / SBN), 256, 0, stream>>>(
        opt_bf, kwd_bf, d_Kb, qp_d, d_vw, s_opt, 0, 5 * LO);
    softmax_kernel<<<NB * 5, 256, 0, stream>>>(s_opt, LO);
    wsum_kernel<<<dim3(NB * 5 * 4, 1), 256, 0, stream>>>(options, s_opt, wd, LO, LO);
    proj_kernel<<<dim3(NB * 5, 4), 256, 0, stream>>>(wd, d_Vw, d_Vb, feats);
    final_kernel<<<NB, 256, 0, stream>>>(feats, f_w, f_b, out);
}

// Round 7
// 443.021 us; speedup vs baseline: 5.2661x; 1.2221x over previous
//
#include <hip/hip_runtime.h>
#include <hip/hip_bf16.h>
#include <math.h>

#define HDIM 1024
#define NB 32
#define LA 2048
#define LO 32

typedef __attribute__((ext_vector_type(8))) short bf16x8;
typedef __attribute__((ext_vector_type(4))) float f32x4;
typedef unsigned int u32;

__device__ __forceinline__ float tanh_fast(float x){
    return 2.0f / (1.0f + __expf(-2.0f * x)) - 1.0f;
}

__device__ __forceinline__ void load_lds16(const void* gptr, void* lptr){
    __builtin_amdgcn_global_load_lds(
        (const __attribute__((address_space(1))) u32*)gptr,
        (__attribute__((address_space(3))) u32*)lptr, 16, 0, 0);
}

__global__ void zero_kernel(float* __restrict__ p, int n){
    int i = blockIdx.x * blockDim.x + threadIdx.x;
    int stride = gridDim.x * blockDim.x;
    for (; i < n; i += stride) p[i] = 0.0f;
}

__global__ void conv_bf16_kernel(const float* __restrict__ in, __hip_bfloat16* __restrict__ out, long n){
    long i = ((long)blockIdx.x * blockDim.x + threadIdx.x) * 4;
    long stride = (long)gridDim.x * blockDim.x * 4;
    for (; i < n; i += stride){
        float4 v = *(const float4*)(in + i);
        union { __hip_bfloat16 h[4]; short4 s; } u;
        u.h[0] = __float2bfloat16(v.x); u.h[1] = __float2bfloat16(v.y);
        u.h[2] = __float2bfloat16(v.z); u.h[3] = __float2bfloat16(v.w);
        *(short4*)(out + i) = u.s;
    }
}

__global__ void gather_kernel(const float* __restrict__ qc, const int* __restrict__ ans,
                              float* __restrict__ oqc){
    int b = blockIdx.x, tid = threadIdx.x;
    int idx = ans[b];
    const float* src = qc + ((size_t)b * 64 + idx) * HDIM;
    float* dst = oqc + (size_t)b * HDIM;
    #pragma unroll
    for (int l = 0; l < 4; l++) dst[tid + l * 256] = src[tid + l * 256];
}

// out[g,h] = bias[h] + dot(in[g,:], W[h,:])   grid (G, 16), block 256 (4 waves).
// One wave per h-row: each lane covers 4 float4 chunks at (c*64+lane)*4, so the
// wave reads the FULL 1024-float W row (4 coalesced 1KB passes); shfl_xor reduce.
__global__ __launch_bounds__(256) void proj_kernel(
    const float* __restrict__ in, const float* __restrict__ W,
    const float* __restrict__ bias, float* __restrict__ out){
    __shared__ float xin[HDIM];
    const int g = blockIdx.x, tid = threadIdx.x;
    const int lane = tid & 63, wave = tid >> 6;
    *(float4*)&xin[tid * 4] = *(const float4*)&in[(size_t)g * HDIM + tid * 4];
    __syncthreads();
    float4 xv[4];
    #pragma unroll
    for (int c = 0; c < 4; c++) xv[c] = *(const float4*)&xin[(c * 64 + lane) * 4];
    const int hbase = blockIdx.y * 64 + wave * 16;
    #pragma unroll 4
    for (int r = 0; r < 16; r++){
        int h = hbase + r;
        const float* Wr = W + (size_t)h * HDIM;
        float p = 0.f;
        #pragma unroll
        for (int c = 0; c < 4; c++){
            float4 wv = *(const float4*)&Wr[(c * 64 + lane) * 4];
            p = fmaf(xv[c].x, wv.x, p); p = fmaf(xv[c].y, wv.y, p);
            p = fmaf(xv[c].z, wv.z, p); p = fmaf(xv[c].w, wv.w, p);
        }
        #pragma unroll
        for (int off = 1; off < 64; off <<= 1) p += __shfl_xor(p, off, 64);
        if (lane == 0) out[(size_t)g * HDIM + h] = p + bias[h];
    }
}

// ---------------- 128x128 deep-pipelined article score kernel -----------------
// C[h, article] = Kw (A) x article (B). 8 waves: wm (2 h-halves of 64),
// wn (4 article quarters of 32). BK=64, 2-buffer counted-vmcnt pipeline.
// XCD-aware decode (requires na % 8 == 0). All loop-invariant addressing
// hoisted: 4 global src pointers advanced +128/tile, 12 precomputed swizzled
// LDS offsets, buffer toggle via one XOR.
#define NT 16   // K tiles = 1024/64
__global__ __launch_bounds__(512, 4) void score_mfma128_kernel(
    const __hip_bfloat16* __restrict__ X, const __hip_bfloat16* __restrict__ Kw,
    const float* __restrict__ Kb, const float* __restrict__ Qp,
    const float* __restrict__ vw, float* __restrict__ s,
    int row_off, int rows_per_batch)
{
    // A (Kw): 2 bufs x 16KB at 0; B (article): 2 bufs x 16KB at 32768
    __shared__ __align__(16) char lds[65536];
    const int tid = threadIdx.x;
    const int lane = tid & 63, wid = tid >> 6;
    const int wm = wid >> 2, wn = wid & 3;
    const int lr = lane & 15, lg = lane >> 4;

    const int na = gridDim.x >> 3;          // article tiles
    const int per = na >> 3;                // a-tiles per XCD
    const int bid = blockIdx.x;
    const int xcd = bid & 7, seq = bid >> 3;
    const int a_idx = xcd * per + (seq >> 3);
    const int h_idx = seq & 7;
    const int a0 = a_idx * 128;             // article row base (within chunk)
    const int h0 = h_idx * 128;             // h base

    f32x4 acc[4][2] = {};

    // ---- hoisted staging pointers (advance +128 bytes per staged tile) ----
    const int rw_c0 = tid >> 3,  srcb_c0 = ((tid & 7) * 16) ^ ((rw_c0 & 7) << 4);
    const int rw_c1 = rw_c0 + 64, srcb_c1 = ((tid & 7) * 16) ^ ((rw_c1 & 7) << 4);
    const char* pA0 = (const char*)Kw + (size_t)(h0 + rw_c0) * 2048 + srcb_c0;
    const char* pA1 = (const char*)Kw + (size_t)(h0 + rw_c1) * 2048 + srcb_c1;
    const char* pB0 = (const char*)X  + (size_t)(a0 + rw_c0) * 2048 + srcb_c0;
    const char* pB1 = (const char*)X  + (size_t)(a0 + rw_c1) * 2048 + srcb_c1;
    char* dA0 = lds + tid * 16;
    char* dA1 = lds + 8192 + tid * 16;
    char* dB0 = lds + 32768 + tid * 16;
    char* dB1 = lds + 32768 + 8192 + tid * 16;

    // ---- hoisted swizzled LDS read offsets ----
    int aoff[4][2], boff[2][2];
    #pragma unroll
    for (int hf = 0; hf < 4; hf++){
        int rw = wm * 64 + hf * 16 + lr;
        int o0 = rw * 128 + ((lg * 16) ^ ((rw & 7) << 4));
        aoff[hf][0] = o0; aoff[hf][1] = o0 ^ 64;
    }
    #pragma unroll
    for (int af = 0; af < 2; af++){
        int rw = wn * 32 + af * 16 + lr;
        int o0 = 32768 + rw * 128 + ((lg * 16) ^ ((rw & 7) << 4));
        boff[af][0] = o0; boff[af][1] = o0 ^ 64;
    }

#define STAGE_ADV(bufoff) do { \
    load_lds16(pA0, dA0 + (bufoff)); load_lds16(pA1, dA1 + (bufoff)); \
    load_lds16(pB0, dB0 + (bufoff)); load_lds16(pB1, dB1 + (bufoff)); \
    pA0 += 128; pA1 += 128; pB0 += 128; pB1 += 128; } while(0)

#define COMPUTE(bufoff) do { \
    _Pragma("unroll") \
    for (int ks = 0; ks < 2; ks++){ \
        bf16x8 av[4], bv[2]; \
        _Pragma("unroll") \
        for (int hf = 0; hf < 4; hf++) \
            av[hf] = *(const bf16x8*)(lds + (bufoff) + aoff[hf][ks]); \
        _Pragma("unroll") \
        for (int af = 0; af < 2; af++) \
            bv[af] = *(const bf16x8*)(lds + (bufoff) + boff[af][ks]); \
        __builtin_amdgcn_s_setprio(1); \
        _Pragma("unroll") \
        for (int hf = 0; hf < 4; hf++) \
            _Pragma("unroll") \
            for (int af = 0; af < 2; af++) \
                acc[hf][af] = __builtin_amdgcn_mfma_f32_16x16x32_bf16(av[hf], bv[af], acc[hf][af], 0, 0, 0); \
        __builtin_amdgcn_s_setprio(0); \
    } } while(0)

    STAGE_ADV(0);
    STAGE_ADV(16384);
    int bo = 0;
    for (int kt = 0; kt < NT - 1; ++kt){
        asm volatile("s_waitcnt vmcnt(4)" ::: "memory");
        __builtin_amdgcn_s_barrier();
        __builtin_amdgcn_sched_barrier(0);
        COMPUTE(bo);
        __builtin_amdgcn_s_barrier();
        if (kt < NT - 2) STAGE_ADV(bo);
        bo ^= 16384;
    }
    asm volatile("s_waitcnt vmcnt(0)" ::: "memory");
    __builtin_amdgcn_s_barrier();
    __builtin_amdgcn_sched_barrier(0);
    COMPUTE(bo);

    // epilogue: per-lane h rows = lg*4+reg within each 16-frag; article col = lr
    const int b = (row_off + a0) / rows_per_batch;  // uniform: 128 | 2048
    float qv[4][4], vv[4][4];
    #pragma unroll
    for (int hf = 0; hf < 4; hf++){
        int hbase = h0 + wm * 64 + hf * 16 + lg * 4;
        float4 kb4 = *(const float4*)(Kb + hbase);
        float4 qp4 = *(const float4*)(Qp + (size_t)b * HDIM + hbase);
        float4 vw4 = *(const float4*)(vw + hbase);
        qv[hf][0] = kb4.x + qp4.x; qv[hf][1] = kb4.y + qp4.y;
        qv[hf][2] = kb4.z + qp4.z; qv[hf][3] = kb4.w + qp4.w;
        vv[hf][0] = vw4.x; vv[hf][1] = vw4.y; vv[hf][2] = vw4.z; vv[hf][3] = vw4.w;
    }
    #pragma unroll
    for (int af = 0; af < 2; af++){
        float sacc = 0.f;
        #pragma unroll
        for (int hf = 0; hf < 4; hf++)
            #pragma unroll
            for (int r = 0; r < 4; r++)
                sacc += tanh_fast(acc[hf][af][r] + qv[hf][r]) * vv[hf][r];
        sacc += __shfl_xor(sacc, 16, 64);
        sacc += __shfl_xor(sacc, 32, 64);
        if (lane < 16)
            atomicAdd(&s[row_off + a0 + wn * 32 + af * 16 + lr], sacc);
    }
#undef STAGE_ADV
#undef COMPUTE
}

// ---------------- old 128x128 4-wave score kernel (option path) --------------
#define SBM 128
#define SBN 128
__global__ __launch_bounds__(256) void score_mfma_kernel(
    const __hip_bfloat16* __restrict__ X, const __hip_bfloat16* __restrict__ Kw,
    const float* __restrict__ Kb, const float* __restrict__ Qp,
    const float* __restrict__ vw, float* __restrict__ s,
    int row_off, int rows_per_batch)
{
    __shared__ __align__(16) __hip_bfloat16 As[SBM][32];
    __shared__ __align__(16) __hip_bfloat16 Bs[SBN][32];
    const int tid = threadIdx.x;
    const int lane = tid & 63, wid = tid >> 6;
    const int wm = wid >> 1, wn = wid & 1;
    const int row0 = blockIdx.x * SBM;
    const int h0 = blockIdx.y * SBN;
    const int lr = lane & 15, lg = lane >> 4;

    f32x4 acc[4][4] = {};

    for (int k0 = 0; k0 < HDIM; k0 += 32){
        #pragma unroll
        for (int l = 0; l < 2; l++){
            int f = tid + l * 256;
            int r = f >> 2, c8 = (f & 3) * 8;
            load_lds16(X + (size_t)(row0 + r) * HDIM + k0 + c8, &As[0][0] + f * 8);
            load_lds16(Kw + (size_t)(h0 + r) * HDIM + k0 + c8, &Bs[0][0] + f * 8);
        }
        __syncthreads();
        bf16x8 a[4], b[4];
        #pragma unroll
        for (int i = 0; i < 4; i++)
            a[i] = *(const bf16x8*)&As[wm * 64 + i * 16 + lr][lg * 8];
        #pragma unroll
        for (int j = 0; j < 4; j++)
            b[j] = *(const bf16x8*)&Bs[wn * 64 + j * 16 + lr][lg * 8];
        #pragma unroll
        for (int i = 0; i < 4; i++)
            #pragma unroll
            for (int j = 0; j < 4; j++)
                acc[i][j] = __builtin_amdgcn_mfma_f32_16x16x32_bf16(a[i], b[j], acc[i][j], 0, 0, 0);
        __syncthreads();
    }

    float kbv[4], vwv[4];
    #pragma unroll
    for (int j = 0; j < 4; j++){
        int h = h0 + wn * 64 + j * 16 + lr;
        kbv[j] = Kb[h]; vwv[j] = vw[h];
    }
    #pragma unroll
    for (int i = 0; i < 4; i++){
        #pragma unroll
        for (int reg = 0; reg < 4; reg++){
            int r = row0 + wm * 64 + i * 16 + lg * 4 + reg;
            int gr = row_off + r;
            int bb = gr / rows_per_batch;
            const float* Qpb = Qp + (size_t)bb * HDIM;
            float p = 0.f;
            #pragma unroll
            for (int j = 0; j < 4; j++){
                int h = h0 + wn * 64 + j * 16 + lr;
                p += tanh_fast(acc[i][j][reg] + kbv[j] + Qpb[h]) * vwv[j];
            }
            #pragma unroll
            for (int off = 1; off < 16; off <<= 1) p += __shfl_xor(p, off, 16);
            if (lr == 0) atomicAdd(&s[gr], p);
        }
    }
}

// in-place softmax over groups of Rg, grid = G blocks of 256
__global__ void softmax_kernel(float* __restrict__ s, int Rg){
    __shared__ float red[4];
    int g = blockIdx.x, tid = threadIdx.x;
    float* sg = s + (size_t)g * Rg;
    float m = -INFINITY;
    for (int i = tid; i < Rg; i += 256) m = fmaxf(m, sg[i]);
    #pragma unroll
    for (int off = 32; off > 0; off >>= 1) m = fmaxf(m, __shfl_down(m, off, 64));
    if ((tid & 63) == 0) red[tid >> 6] = m;
    __syncthreads();
    m = fmaxf(fmaxf(red[0], red[1]), fmaxf(red[2], red[3]));
    __syncthreads();
    float sum = 0.f;
    for (int i = tid; i < Rg; i += 256){ float e = __expf(sg[i] - m); sg[i] = e; sum += e; }
    #pragma unroll
    for (int off = 32; off > 0; off >>= 1) sum += __shfl_down(sum, off, 64);
    if ((tid & 63) == 0) red[tid >> 6] = sum;
    __syncthreads();
    float inv = 1.0f / (red[0] + red[1] + red[2] + red[3]);
    for (int i = tid; i < Rg; i += 256) sg[i] *= inv;
}

// f32 weighted sum (options / fallback)
__global__ void wsum_kernel(const float* __restrict__ X, const float* __restrict__ sc,
                            float* __restrict__ out, int Rg, int rowsPerChunk){
    __shared__ float scs[256];
    int g = blockIdx.x >> 2;
    int kc = blockIdx.x & 3;
    int i0 = blockIdx.y * rowsPerChunk;
    int tid = threadIdx.x;
    if (tid < rowsPerChunk) scs[tid] = sc[(size_t)g * Rg + i0 + tid];
    __syncthreads();
    int k = kc * 256 + tid;
    const float* Xg = X + ((size_t)g * Rg + i0) * HDIM + k;
    float acc = 0.f;
    for (int i = 0; i < rowsPerChunk; i++)
        acc += scs[i] * Xg[(size_t)i * HDIM];
    atomicAdd(&out[(size_t)g * HDIM + k], acc);
}

// bf16-input weighted sum (article)
__global__ void wsum_bf16_kernel(const __hip_bfloat16* __restrict__ X, const float* __restrict__ sc,
                                 float* __restrict__ out, int Rg, int rowsPerChunk){
    __shared__ float scs[256];
    int g = blockIdx.x >> 2;
    int kc = blockIdx.x & 3;
    int i0 = blockIdx.y * rowsPerChunk;
    int tid = threadIdx.x;
    if (tid < rowsPerChunk) scs[tid] = sc[(size_t)g * Rg + i0 + tid];
    __syncthreads();
    int k = kc * 256 + tid;
    const __hip_bfloat16* Xg = X + ((size_t)g * Rg + i0) * HDIM + k;
    float acc = 0.f;
    for (int i = 0; i < rowsPerChunk; i++)
        acc += scs[i] * __bfloat162float(Xg[(size_t)i * HDIM]);
    atomicAdd(&out[(size_t)g * HDIM + k], acc);
}

// logits[b,j] = fb[j] + dot(feats[b,:5120], fw[j,:5120])  grid 32, block 256
__global__ void final_kernel(const float* __restrict__ feats, const float* __restrict__ fw,
                             const float* __restrict__ fb, float* __restrict__ out){
    __shared__ float red[4];
    int b = blockIdx.x, tid = threadIdx.x;
    const float* fe = feats + (size_t)b * 5120;
    for (int j = 0; j < 5; j++){
        float acc = 0.f;
        for (int i = tid; i < 5120; i += 256) acc += fe[i] * fw[(size_t)j * 5120 + i];
        #pragma unroll
        for (int off = 32; off > 0; off >>= 1) acc += __shfl_down(acc, off, 64);
        if ((tid & 63) == 0) red[tid >> 6] = acc;
        __syncthreads();
        if (tid == 0) out[b * 5 + j] = fb[j] + red[0] + red[1] + red[2] + red[3];
        __syncthreads();
    }
}

extern "C" void kernel_launch(void* const* d_in, const int* in_sizes, int n_in,
                              void* d_out, int out_size, void* d_ws, size_t ws_size,
                              hipStream_t stream) {
    const float* article  = (const float*)d_in[0];
    const float* question = (const float*)d_in[1];
    const float* options  = (const float*)d_in[2];
    const int*   ans      = (const int*)d_in[3];
    const float* a_Qw = (const float*)d_in[4];  const float* a_Qb = (const float*)d_in[5];
    const float* a_Kw = (const float*)d_in[6];  const float* a_Kb = (const float*)d_in[7];
    const float* a_Vw = (const float*)d_in[8];  const float* a_Vb = (const float*)d_in[9];
    const float* a_vw = (const float*)d_in[10];
    const float* d_Qw = (const float*)d_in[12]; const float* d_Qb = (const float*)d_in[13];
    const float* d_Kw = (const float*)d_in[14]; const float* d_Kb = (const float*)d_in[15];
    const float* d_Vw = (const float*)d_in[16]; const float* d_Vb = (const float*)d_in[17];
    const float* d_vw = (const float*)d_in[18];
    const float* f_w  = (const float*)d_in[20]; const float* f_b  = (const float*)d_in[21];
    float* out = (float*)d_out;

    float* ws = (float*)d_ws;
    float* oqc   = ws;               // 32768
    float* qp_a  = ws + 32768;       // 32768
    float* aq    = ws + 65536;       // 32768
    float* qp_d  = ws + 98304;       // 32768
    float* feats = ws + 131072;      // 163840
    float* s_art = ws + 294912;      // 65536  (zeroed)
    float* s_opt = ws + 360448;      // 5120   (zeroed)
    float* w_art = ws + 365568;      // 32768  (zeroed)
    float* wd    = ws + 398336;      // 163840 (zeroed)
    // bf16 region
    __hip_bfloat16* kwa_bf = (__hip_bfloat16*)(ws + 562176);
    __hip_bfloat16* kwd_bf = kwa_bf + 1048576;
    __hip_bfloat16* opt_bf = kwd_bf + 1048576;       // 5242880 elems
    __hip_bfloat16* art_bf = opt_bf + 5242880;
    size_t used_bytes = 562176 * 4 + (size_t)(1048576 * 2 + 5242880) * 2;
    long avail_rows = (long)((ws_size - used_bytes) / (HDIM * 2));
    int rows_total = NB * LA;  // 65536
    int chunk_rows = (int)(avail_rows < rows_total ? avail_rows : rows_total);
    chunk_rows &= ~1023;               // na (= chunk/128) must be a multiple of 8
    if (chunk_rows < 1024) chunk_rows = 1024;

    zero_kernel<<<256, 256, 0, stream>>>(s_art, 267264);
    gather_kernel<<<NB, 256, 0, stream>>>(question, ans, oqc);
    proj_kernel<<<dim3(NB, 16), 256, 0, stream>>>(oqc, a_Qw, a_Qb, qp_a);
    conv_bf16_kernel<<<64, 256, 0, stream>>>(a_Kw, kwa_bf, 1048576);

    for (int r0 = 0; r0 < rows_total; r0 += chunk_rows){
        int nr = rows_total - r0; if (nr > chunk_rows) nr = chunk_rows;
        conv_bf16_kernel<<<1024, 256, 0, stream>>>(article + (size_t)r0 * HDIM, art_bf, (long)nr * HDIM);
        score_mfma128_kernel<<<(nr / 128) * 8, 512, 0, stream>>>(
            art_bf, kwa_bf, a_Kb, qp_a, a_vw, s_art, r0, LA);
    }
    softmax_kernel<<<NB, 256, 0, stream>>>(s_art, LA);
    if (chunk_rows >= rows_total)
        wsum_bf16_kernel<<<dim3(NB * 4, 8), 256, 0, stream>>>(art_bf, s_art, w_art, LA, 256);
    else
        wsum_kernel<<<dim3(NB * 4, 8), 256, 0, stream>>>(article, s_art, w_art, LA, 256);
    proj_kernel<<<dim3(NB, 16), 256, 0, stream>>>(w_art, a_Vw, a_Vb, aq);

    proj_kernel<<<dim3(NB, 16), 256, 0, stream>>>(aq, d_Qw, d_Qb, qp_d);
    conv_bf16_kernel<<<64, 256, 0, stream>>>(d_Kw, kwd_bf, 1048576);
    conv_bf16_kernel<<<320, 256, 0, stream>>>(options, opt_bf, 5242880);
    score_mfma_kernel<<<dim3((NB * 5 * LO) / SBM, HDIM / SBN), 256, 0, stream>>>(
        opt_bf, kwd_bf, d_Kb, qp_d, d_vw, s_opt, 0, 5 * LO);
    softmax_kernel<<<NB * 5, 256, 0, stream>>>(s_opt, LO);
    wsum_kernel<<<dim3(NB * 5 * 4, 1), 256, 0, stream>>>(options, s_opt, wd, LO, LO);
    proj_kernel<<<dim3(NB * 5, 16), 256, 0, stream>>>(wd, d_Vw, d_Vb, feats);
    final_kernel<<<NB, 256, 0, stream>>>(feats, f_w, f_b, out);
}